// Round 1
// baseline (7558.955 us; speedup 1.0000x reference)
//
#include <hip/hip_runtime.h>
#include <hip/hip_bf16.h>

#define N_LIG 100000
#define N_TGT 20000
#define NEDGE 1000000
#define H 128

// ---------------- zero fill (float4) ----------------
__global__ void zero_f4(float4* __restrict__ p, long n4) {
    long i = (long)blockIdx.x * blockDim.x + threadIdx.x;
    long stride = (long)gridDim.x * blockDim.x;
    for (; i < n4; i += stride) p[i] = make_float4(0.f, 0.f, 0.f, 0.f);
}

// ---------------- ligand embed: K=4 ----------------
__global__ void lin4_kernel(const float* __restrict__ X, const float* __restrict__ W,
                            const float* __restrict__ b, float* __restrict__ Y, int N) {
    int idx = blockIdx.x * blockDim.x + threadIdx.x;  // over N*32 float4 chunks
    if (idx >= N * 32) return;
    int r = idx >> 5;
    int c = (idx & 31) * 4;
    float x0 = X[r * 4 + 0], x1 = X[r * 4 + 1], x2 = X[r * 4 + 2], x3 = X[r * 4 + 3];
    float4 acc = *(const float4*)&b[c];
    float4 w0 = *(const float4*)&W[0 * H + c];
    float4 w1 = *(const float4*)&W[1 * H + c];
    float4 w2 = *(const float4*)&W[2 * H + c];
    float4 w3 = *(const float4*)&W[3 * H + c];
    acc.x += x0 * w0.x + x1 * w1.x + x2 * w2.x + x3 * w3.x;
    acc.y += x0 * w0.y + x1 * w1.y + x2 * w2.y + x3 * w3.y;
    acc.z += x0 * w0.z + x1 * w1.z + x2 * w2.z + x3 * w3.z;
    acc.w += x0 * w0.w + x1 * w1.w + x2 * w2.w + x3 * w3.w;
    *(float4*)&Y[(size_t)r * H + c] = acc;
}

// ---------------- generic GEMM: Y[N][128] = act(scale(X) @ W[K][128] + bias) ----------------
// K must be a multiple of 128. rowscale: optional per-row multiplier (mean-agg fold).
__launch_bounds__(256)
__global__ void linear128(const float* __restrict__ X, const float* __restrict__ rowscale,
                          const float* __restrict__ W, const float* __restrict__ bias,
                          float* __restrict__ Y, int N, int K, int do_relu) {
    __shared__ float Xs[64][128];    // 32 KB
    __shared__ float Ws[128][128];   // 64 KB
    const int t = threadIdx.x;
    const int tx = t & 15;           // col group: cols tx*8..tx*8+7
    const int ty = t >> 4;           // row group: rows ty*4..ty*4+3
    const int row0 = blockIdx.x * 64;

    float acc[4][8];
#pragma unroll
    for (int i = 0; i < 4; i++)
#pragma unroll
        for (int j = 0; j < 8; j++) acc[i][j] = 0.f;

    for (int k0 = 0; k0 < K; k0 += 128) {
        // stage X tile: 64 rows x 32 float4 = 2048 f4 -> 8 per thread
#pragma unroll
        for (int i = 0; i < 8; ++i) {
            int li = t + i * 256;
            int r = li >> 5, c4 = li & 31;
            int gr = row0 + r;
            float4 v = make_float4(0.f, 0.f, 0.f, 0.f);
            if (gr < N) {
                v = *(const float4*)&X[(size_t)gr * K + k0 + c4 * 4];
                if (rowscale) {
                    float s = rowscale[gr];
                    v.x *= s; v.y *= s; v.z *= s; v.w *= s;
                }
            }
            *(float4*)&Xs[r][c4 * 4] = v;
        }
        // stage W tile: 128 rows x 32 float4 = 4096 f4 -> 16 per thread
#pragma unroll
        for (int i = 0; i < 16; ++i) {
            int li = t + i * 256;
            int r = li >> 5, c4 = li & 31;
            *(float4*)&Ws[r][c4 * 4] = *(const float4*)&W[(size_t)(k0 + r) * H + c4 * 4];
        }
        __syncthreads();
#pragma unroll 4
        for (int k = 0; k < 128; ++k) {
            float aa[4];
            aa[0] = Xs[ty * 4 + 0][k];
            aa[1] = Xs[ty * 4 + 1][k];
            aa[2] = Xs[ty * 4 + 2][k];
            aa[3] = Xs[ty * 4 + 3][k];
            float4 b0 = *(const float4*)&Ws[k][tx * 8];
            float4 b1 = *(const float4*)&Ws[k][tx * 8 + 4];
            float bb[8] = {b0.x, b0.y, b0.z, b0.w, b1.x, b1.y, b1.z, b1.w};
#pragma unroll
            for (int i = 0; i < 4; i++)
#pragma unroll
                for (int j = 0; j < 8; j++) acc[i][j] = fmaf(aa[i], bb[j], acc[i][j]);
        }
        __syncthreads();
    }
    // epilogue
    float bvals[8];
#pragma unroll
    for (int j = 0; j < 8; j++) bvals[j] = bias ? bias[tx * 8 + j] : 0.f;
#pragma unroll
    for (int i = 0; i < 4; i++) {
        int gr = row0 + ty * 4 + i;
        if (gr >= N) continue;
        float o[8];
#pragma unroll
        for (int j = 0; j < 8; j++) {
            float v = acc[i][j] + bvals[j];
            o[j] = do_relu ? fmaxf(v, 0.f) : v;
        }
        *(float4*)&Y[(size_t)gr * H + tx * 8] = make_float4(o[0], o[1], o[2], o[3]);
        *(float4*)&Y[(size_t)gr * H + tx * 8 + 4] = make_float4(o[4], o[5], o[6], o[7]);
    }
}

// ---------------- edge degree counts ----------------
__global__ void count_kernel(const int* __restrict__ es, const int* __restrict__ ed,
                             float* __restrict__ cs, float* __restrict__ cd, int E) {
    int i = blockIdx.x * blockDim.x + threadIdx.x;
    int stride = gridDim.x * blockDim.x;
    for (; i < E; i += stride) {
        atomicAdd(&cs[es[i]], 1.f);
        atomicAdd(&cd[ed[i]], 1.f);
    }
}

__global__ void invert_kernel(float* __restrict__ c, int n) {
    int i = blockIdx.x * blockDim.x + threadIdx.x;
    if (i < n) c[i] = 1.f / fmaxf(c[i], 1.f);
}

// ---------------- scatter-add: agg[to[e]] += feat[from[e]] ----------------
__global__ void scatter_add_kernel(const float* __restrict__ feat, const int* __restrict__ from_idx,
                                   const int* __restrict__ to_idx, float* __restrict__ agg, int E) {
    long i = (long)blockIdx.x * blockDim.x + threadIdx.x;
    if (i >= (long)E * 32) return;
    int e = (int)(i >> 5);
    int c = (int)(i & 31) * 4;
    int s = from_idx[e];
    int d = to_idx[e];
    float4 v = *(const float4*)&feat[(size_t)s * H + c];
    float* dst = &agg[(size_t)d * H + c];
    atomicAdd(dst + 0, v.x);
    atomicAdd(dst + 1, v.y);
    atomicAdd(dst + 2, v.z);
    atomicAdd(dst + 3, v.w);
}

// ---------------- edge MLP: pred[e] = relu(A[s]+B[d]) . Wp2 + bp2 ----------------
// 16 lanes per edge, each lane handles 8 features.
__global__ void edge_mlp_kernel(const float* __restrict__ A, const float* __restrict__ B,
                                const int* __restrict__ es, const int* __restrict__ ed,
                                const float* __restrict__ Wp2, const float* __restrict__ bp2,
                                float* __restrict__ out, int E) {
    long gid = (long)blockIdx.x * blockDim.x + threadIdx.x;
    long e = gid >> 4;
    if (e >= E) return;
    int l16 = (int)(threadIdx.x & 15);
    int s = es[e], d = ed[e];
    const float4* pa = (const float4*)&A[(size_t)s * H + l16 * 8];
    const float4* pb = (const float4*)&B[(size_t)d * H + l16 * 8];
    const float4* pw = (const float4*)&Wp2[l16 * 8];
    float4 a0 = pa[0], a1 = pa[1];
    float4 b0 = pb[0], b1 = pb[1];
    float4 w0 = pw[0], w1 = pw[1];
    float acc = fmaxf(a0.x + b0.x, 0.f) * w0.x + fmaxf(a0.y + b0.y, 0.f) * w0.y +
                fmaxf(a0.z + b0.z, 0.f) * w0.z + fmaxf(a0.w + b0.w, 0.f) * w0.w +
                fmaxf(a1.x + b1.x, 0.f) * w1.x + fmaxf(a1.y + b1.y, 0.f) * w1.y +
                fmaxf(a1.z + b1.z, 0.f) * w1.z + fmaxf(a1.w + b1.w, 0.f) * w1.w;
    acc += __shfl_xor(acc, 8);
    acc += __shfl_xor(acc, 4);
    acc += __shfl_xor(acc, 2);
    acc += __shfl_xor(acc, 1);
    if (l16 == 0) out[e] = acc + bp2[0];
}

extern "C" void kernel_launch(void* const* d_in, const int* in_sizes, int n_in,
                              void* d_out, int out_size, void* d_ws, size_t ws_size,
                              hipStream_t stream) {
    const float* x_lig = (const float*)d_in[0];
    const float* x_tgt = (const float*)d_in[1];
    const int* es = (const int*)d_in[2];
    const int* ed = (const int*)d_in[3];
    const float* W_lig = (const float*)d_in[4];
    const float* b_lig = (const float*)d_in[5];
    const float* W_tgt = (const float*)d_in[6];
    const float* b_tgt = (const float*)d_in[7];
    const float* W1f = (const float*)d_in[8];
    const float* b1f = (const float*)d_in[9];
    const float* W1r = (const float*)d_in[10];
    const float* b1r = (const float*)d_in[11];
    const float* W2f = (const float*)d_in[12];
    const float* b2f = (const float*)d_in[13];
    const float* W2r = (const float*)d_in[14];
    const float* b2r = (const float*)d_in[15];
    const float* Wp1 = (const float*)d_in[16];
    const float* bp1 = (const float*)d_in[17];
    const float* Wp2 = (const float*)d_in[18];
    const float* bp2 = (const float*)d_in[19];
    float* out = (float*)d_out;

    float* ws = (float*)d_ws;
    size_t off = 0;
    float* L0 = ws + off; off += (size_t)N_LIG * H;   // h_lig (ping)
    float* L1 = ws + off; off += (size_t)N_LIG * H;   // agg_l / h_lig (pong) / A
    float* T0 = ws + off; off += (size_t)N_TGT * H;   // h_tgt (ping)
    float* T1 = ws + off; off += (size_t)N_TGT * H;   // agg_t / B
    float* invs = ws + off; off += N_LIG;             // 1/deg(ligand)
    float* invd = ws + off; off += N_TGT;             // 1/deg(target)

    const int ligBlocks = (N_LIG + 63) / 64;
    const int tgtBlocks = (N_TGT + 63) / 64;

    // 1. node embeddings
    lin4_kernel<<<(N_LIG * 32 + 255) / 256, 256, 0, stream>>>(x_lig, W_lig, b_lig, L0, N_LIG);
    linear128<<<tgtBlocks, 256, 0, stream>>>(x_tgt, nullptr, W_tgt, b_tgt, T0, N_TGT, 1280, 0);

    // 2. degree counts (shared by both convs)
    zero_f4<<<120, 256, 0, stream>>>((float4*)invs, (N_LIG + N_TGT) / 4);
    count_kernel<<<2048, 256, 0, stream>>>(es, ed, invs, invd, NEDGE);
    invert_kernel<<<(N_LIG + 255) / 256, 256, 0, stream>>>(invs, N_LIG);
    invert_kernel<<<(N_TGT + 255) / 256, 256, 0, stream>>>(invd, N_TGT);

    // 3. two conv layers
    const float* Wf[2] = {W1f, W2f};
    const float* bf[2] = {b1f, b2f};
    const float* Wr[2] = {W1r, W2r};
    const float* br[2] = {b1r, b2r};
    for (int layer = 0; layer < 2; ++layer) {
        zero_f4<<<4096, 256, 0, stream>>>((float4*)L1, (long)N_LIG * H / 4);
        zero_f4<<<2048, 256, 0, stream>>>((float4*)T1, (long)N_TGT * H / 4);
        scatter_add_kernel<<<(int)(((long)NEDGE * 32 + 255) / 256), 256, 0, stream>>>(L0, es, ed, T1, NEDGE);
        scatter_add_kernel<<<(int)(((long)NEDGE * 32 + 255) / 256), 256, 0, stream>>>(T0, ed, es, L1, NEDGE);
        linear128<<<tgtBlocks, 256, 0, stream>>>(T1, invd, Wf[layer], bf[layer], T0, N_TGT, H, 1);
        linear128<<<ligBlocks, 256, 0, stream>>>(L1, invs, Wr[layer], br[layer], L0, N_LIG, H, 1);
    }

    // 4. edge-MLP factorization: A = h_lig @ Wp1_top; B = h_tgt @ Wp1_bot + bp1
    linear128<<<ligBlocks, 256, 0, stream>>>(L0, nullptr, Wp1, nullptr, L1, N_LIG, H, 0);
    linear128<<<tgtBlocks, 256, 0, stream>>>(T0, nullptr, Wp1 + 128 * H, bp1, T1, N_TGT, H, 0);

    // 5. per-edge: pred = relu(A[s]+B[d]) . Wp2 + bp2
    edge_mlp_kernel<<<(int)(((long)NEDGE * 16 + 255) / 256), 256, 0, stream>>>(
        L1, T1, es, ed, Wp2, bp2, out, NEDGE);
}

// Round 2
// 1221.530 us; speedup vs baseline: 6.1881x; 6.1881x over previous
//
#include <hip/hip_runtime.h>
#include <hip/hip_bf16.h>

#define N_LIG 100000
#define N_TGT 20000
#define NEDGE 1000000
#define H 128

// ---------------- zero fill (float4 / int4 sized) ----------------
__global__ void zero_f4(float4* __restrict__ p, long n4) {
    long i = (long)blockIdx.x * blockDim.x + threadIdx.x;
    long stride = (long)gridDim.x * blockDim.x;
    for (; i < n4; i += stride) p[i] = make_float4(0.f, 0.f, 0.f, 0.f);
}

// ---------------- ligand embed: K=4 ----------------
__global__ void lin4_kernel(const float* __restrict__ X, const float* __restrict__ W,
                            const float* __restrict__ b, float* __restrict__ Y, int N) {
    int idx = blockIdx.x * blockDim.x + threadIdx.x;  // over N*32 float4 chunks
    if (idx >= N * 32) return;
    int r = idx >> 5;
    int c = (idx & 31) * 4;
    float x0 = X[r * 4 + 0], x1 = X[r * 4 + 1], x2 = X[r * 4 + 2], x3 = X[r * 4 + 3];
    float4 acc = *(const float4*)&b[c];
    float4 w0 = *(const float4*)&W[0 * H + c];
    float4 w1 = *(const float4*)&W[1 * H + c];
    float4 w2 = *(const float4*)&W[2 * H + c];
    float4 w3 = *(const float4*)&W[3 * H + c];
    acc.x += x0 * w0.x + x1 * w1.x + x2 * w2.x + x3 * w3.x;
    acc.y += x0 * w0.y + x1 * w1.y + x2 * w2.y + x3 * w3.y;
    acc.z += x0 * w0.z + x1 * w1.z + x2 * w2.z + x3 * w3.z;
    acc.w += x0 * w0.w + x1 * w1.w + x2 * w2.w + x3 * w3.w;
    *(float4*)&Y[(size_t)r * H + c] = acc;
}

// ---------------- generic GEMM: Y[N][128] = act(X @ W[K][128] + bias) ----------------
__launch_bounds__(256)
__global__ void linear128(const float* __restrict__ X,
                          const float* __restrict__ W, const float* __restrict__ bias,
                          float* __restrict__ Y, int N, int K, int do_relu) {
    __shared__ float Xs[64][128];    // 32 KB
    __shared__ float Ws[128][128];   // 64 KB
    const int t = threadIdx.x;
    const int tx = t & 15;           // col group: cols tx*8..tx*8+7
    const int ty = t >> 4;           // row group: rows ty*4..ty*4+3
    const int row0 = blockIdx.x * 64;

    float acc[4][8];
#pragma unroll
    for (int i = 0; i < 4; i++)
#pragma unroll
        for (int j = 0; j < 8; j++) acc[i][j] = 0.f;

    for (int k0 = 0; k0 < K; k0 += 128) {
#pragma unroll
        for (int i = 0; i < 8; ++i) {
            int li = t + i * 256;
            int r = li >> 5, c4 = li & 31;
            int gr = row0 + r;
            float4 v = make_float4(0.f, 0.f, 0.f, 0.f);
            if (gr < N) v = *(const float4*)&X[(size_t)gr * K + k0 + c4 * 4];
            *(float4*)&Xs[r][c4 * 4] = v;
        }
#pragma unroll
        for (int i = 0; i < 16; ++i) {
            int li = t + i * 256;
            int r = li >> 5, c4 = li & 31;
            *(float4*)&Ws[r][c4 * 4] = *(const float4*)&W[(size_t)(k0 + r) * H + c4 * 4];
        }
        __syncthreads();
#pragma unroll 4
        for (int k = 0; k < 128; ++k) {
            float aa[4];
            aa[0] = Xs[ty * 4 + 0][k];
            aa[1] = Xs[ty * 4 + 1][k];
            aa[2] = Xs[ty * 4 + 2][k];
            aa[3] = Xs[ty * 4 + 3][k];
            float4 b0 = *(const float4*)&Ws[k][tx * 8];
            float4 b1 = *(const float4*)&Ws[k][tx * 8 + 4];
            float bb[8] = {b0.x, b0.y, b0.z, b0.w, b1.x, b1.y, b1.z, b1.w};
#pragma unroll
            for (int i = 0; i < 4; i++)
#pragma unroll
                for (int j = 0; j < 8; j++) acc[i][j] = fmaf(aa[i], bb[j], acc[i][j]);
        }
        __syncthreads();
    }
    float bvals[8];
#pragma unroll
    for (int j = 0; j < 8; j++) bvals[j] = bias ? bias[tx * 8 + j] : 0.f;
#pragma unroll
    for (int i = 0; i < 4; i++) {
        int gr = row0 + ty * 4 + i;
        if (gr >= N) continue;
        float o[8];
#pragma unroll
        for (int j = 0; j < 8; j++) {
            float v = acc[i][j] + bvals[j];
            o[j] = do_relu ? fmaxf(v, 0.f) : v;
        }
        *(float4*)&Y[(size_t)gr * H + tx * 8] = make_float4(o[0], o[1], o[2], o[3]);
        *(float4*)&Y[(size_t)gr * H + tx * 8 + 4] = make_float4(o[4], o[5], o[6], o[7]);
    }
}

// ---------------- CSR build ----------------
__global__ void count2_kernel(const int* __restrict__ es, const int* __restrict__ ed,
                              int* __restrict__ cl, int* __restrict__ ct, int E) {
    int i = blockIdx.x * blockDim.x + threadIdx.x;
    int stride = gridDim.x * blockDim.x;
    for (; i < E; i += stride) {
        atomicAdd(&cl[es[i]], 1);
        atomicAdd(&ct[ed[i]], 1);
    }
}

// hierarchical exclusive scan: 1024 elems per block
__global__ void scan_block_kernel(const int* __restrict__ in, int* __restrict__ out,
                                  int* __restrict__ bsum, int n) {
    __shared__ int ts[256];
    int t = threadIdx.x;
    int base = blockIdx.x * 1024 + t * 4;
    int v[4];
    int s = 0;
#pragma unroll
    for (int i = 0; i < 4; i++) {
        v[i] = (base + i < n) ? in[base + i] : 0;
        s += v[i];
    }
    ts[t] = s;
    __syncthreads();
    for (int ofs = 1; ofs < 256; ofs <<= 1) {
        int x = (t >= ofs) ? ts[t - ofs] : 0;
        __syncthreads();
        ts[t] += x;
        __syncthreads();
    }
    int run = (t == 0) ? 0 : ts[t - 1];
    if (t == 255) bsum[blockIdx.x] = ts[255];
#pragma unroll
    for (int i = 0; i < 4; i++) {
        if (base + i < n) out[base + i] = run;
        run += v[i];
    }
}

__global__ void scan_top_kernel(int* __restrict__ bsum, int nb) {
    __shared__ int ts[256];
    int t = threadIdx.x;
    ts[t] = (t < nb) ? bsum[t] : 0;
    __syncthreads();
    for (int ofs = 1; ofs < 256; ofs <<= 1) {
        int x = (t >= ofs) ? ts[t - ofs] : 0;
        __syncthreads();
        ts[t] += x;
        __syncthreads();
    }
    int excl = (t == 0) ? 0 : ts[t - 1];
    if (t < nb) bsum[t] = excl;
}

__global__ void add_off_kernel(int* __restrict__ out, const int* __restrict__ bsum, int n, int total) {
    int i = blockIdx.x * blockDim.x + threadIdx.x;
    if (i < n) out[i] += bsum[i >> 10];
    if (i == 0) out[n] = total;
}

__global__ void copy_i_kernel(const int* __restrict__ in, int* __restrict__ out, int n) {
    int i = blockIdx.x * blockDim.x + threadIdx.x;
    if (i < n) out[i] = in[i];
}

__global__ void fill_csr_kernel(const int* __restrict__ es, const int* __restrict__ ed,
                                int* __restrict__ cur_l, int* __restrict__ cur_t,
                                int* __restrict__ nbr_l, int* __restrict__ nbr_t, int E) {
    int i = blockIdx.x * blockDim.x + threadIdx.x;
    int stride = gridDim.x * blockDim.x;
    for (; i < E; i += stride) {
        int s = es[i], d = ed[i];
        nbr_l[atomicAdd(&cur_l[s], 1)] = d;
        nbr_t[atomicAdd(&cur_t[d], 1)] = s;
    }
}

// ---------------- gather-mean: out[n] = mean over nbr list of feat rows ----------------
// one wave per node, float2 per lane
__launch_bounds__(256)
__global__ void gather_mean_kernel(const float* __restrict__ feat, const int* __restrict__ rowptr,
                                   const int* __restrict__ nbr, float* __restrict__ out, int N) {
    int wid = (blockIdx.x * blockDim.x + threadIdx.x) >> 6;
    if (wid >= N) return;
    int lane = threadIdx.x & 63;
    int beg = rowptr[wid], end = rowptr[wid + 1];
    const float2* f2 = (const float2*)feat;
    float ax = 0.f, ay = 0.f;
    int j = beg;
    for (; j + 4 <= end; j += 4) {
        int s0 = nbr[j], s1 = nbr[j + 1], s2 = nbr[j + 2], s3 = nbr[j + 3];
        float2 v0 = f2[(size_t)s0 * 64 + lane];
        float2 v1 = f2[(size_t)s1 * 64 + lane];
        float2 v2 = f2[(size_t)s2 * 64 + lane];
        float2 v3 = f2[(size_t)s3 * 64 + lane];
        ax += v0.x + v1.x + v2.x + v3.x;
        ay += v0.y + v1.y + v2.y + v3.y;
    }
    for (; j < end; ++j) {
        float2 v = f2[(size_t)nbr[j] * 64 + lane];
        ax += v.x;
        ay += v.y;
    }
    float inv = 1.f / (float)max(end - beg, 1);
    float2 r;
    r.x = ax * inv;
    r.y = ay * inv;
    ((float2*)out)[(size_t)wid * 64 + lane] = r;
}

// ---------------- edge MLP: pred[e] = relu(A[s]+B[d]) . Wp2 + bp2 ----------------
__global__ void edge_mlp_kernel(const float* __restrict__ A, const float* __restrict__ B,
                                const int* __restrict__ es, const int* __restrict__ ed,
                                const float* __restrict__ Wp2, const float* __restrict__ bp2,
                                float* __restrict__ out, int E) {
    long gid = (long)blockIdx.x * blockDim.x + threadIdx.x;
    long e = gid >> 4;
    if (e >= E) return;
    int l16 = (int)(threadIdx.x & 15);
    int s = es[e], d = ed[e];
    const float4* pa = (const float4*)&A[(size_t)s * H + l16 * 8];
    const float4* pb = (const float4*)&B[(size_t)d * H + l16 * 8];
    const float4* pw = (const float4*)&Wp2[l16 * 8];
    float4 a0 = pa[0], a1 = pa[1];
    float4 b0 = pb[0], b1 = pb[1];
    float4 w0 = pw[0], w1 = pw[1];
    float acc = fmaxf(a0.x + b0.x, 0.f) * w0.x + fmaxf(a0.y + b0.y, 0.f) * w0.y +
                fmaxf(a0.z + b0.z, 0.f) * w0.z + fmaxf(a0.w + b0.w, 0.f) * w0.w +
                fmaxf(a1.x + b1.x, 0.f) * w1.x + fmaxf(a1.y + b1.y, 0.f) * w1.y +
                fmaxf(a1.z + b1.z, 0.f) * w1.z + fmaxf(a1.w + b1.w, 0.f) * w1.w;
    acc += __shfl_xor(acc, 8);
    acc += __shfl_xor(acc, 4);
    acc += __shfl_xor(acc, 2);
    acc += __shfl_xor(acc, 1);
    if (l16 == 0) out[e] = acc + bp2[0];
}

extern "C" void kernel_launch(void* const* d_in, const int* in_sizes, int n_in,
                              void* d_out, int out_size, void* d_ws, size_t ws_size,
                              hipStream_t stream) {
    const float* x_lig = (const float*)d_in[0];
    const float* x_tgt = (const float*)d_in[1];
    const int* es = (const int*)d_in[2];
    const int* ed = (const int*)d_in[3];
    const float* W_lig = (const float*)d_in[4];
    const float* b_lig = (const float*)d_in[5];
    const float* W_tgt = (const float*)d_in[6];
    const float* b_tgt = (const float*)d_in[7];
    const float* W1f = (const float*)d_in[8];
    const float* b1f = (const float*)d_in[9];
    const float* W1r = (const float*)d_in[10];
    const float* b1r = (const float*)d_in[11];
    const float* W2f = (const float*)d_in[12];
    const float* b2f = (const float*)d_in[13];
    const float* W2r = (const float*)d_in[14];
    const float* b2r = (const float*)d_in[15];
    const float* Wp1 = (const float*)d_in[16];
    const float* bp1 = (const float*)d_in[17];
    const float* Wp2 = (const float*)d_in[18];
    const float* bp2 = (const float*)d_in[19];
    float* out = (float*)d_out;

    float* ws = (float*)d_ws;
    size_t off = 0;
    float* L0 = ws + off; off += (size_t)N_LIG * H;   // h_lig (ping)
    float* L1 = ws + off; off += (size_t)N_LIG * H;   // agg_l / A
    float* T0 = ws + off; off += (size_t)N_TGT * H;   // h_tgt (ping)
    float* T1 = ws + off; off += (size_t)N_TGT * H;   // agg_t / B
    int* iws = (int*)(ws + off);
    size_t ioff = 0;
    int* cnt_l = iws + ioff; ioff += N_LIG;
    int* cnt_t = iws + ioff; ioff += N_TGT;
    int* rowptr_l = iws + ioff; ioff += N_LIG + 4;
    int* rowptr_t = iws + ioff; ioff += N_TGT + 4;
    int* cur_l = iws + ioff; ioff += N_LIG;
    int* cur_t = iws + ioff; ioff += N_TGT;
    int* bsum_l = iws + ioff; ioff += 256;
    int* bsum_t = iws + ioff; ioff += 256;
    int* nbr_l = iws + ioff; ioff += NEDGE;   // dst per edge, grouped by src
    int* nbr_t = iws + ioff; ioff += NEDGE;   // src per edge, grouped by dst

    const int ligBlocks = (N_LIG + 63) / 64;
    const int tgtBlocks = (N_TGT + 63) / 64;
    const int nbL = (N_LIG + 1023) / 1024;   // 98
    const int nbT = (N_TGT + 1023) / 1024;   // 20

    // 1. node embeddings
    lin4_kernel<<<(N_LIG * 32 + 255) / 256, 256, 0, stream>>>(x_lig, W_lig, b_lig, L0, N_LIG);
    linear128<<<tgtBlocks, 256, 0, stream>>>(x_tgt, W_tgt, b_tgt, T0, N_TGT, 1280, 0);

    // 2. CSR build (both directions)
    zero_f4<<<120, 256, 0, stream>>>((float4*)cnt_l, (N_LIG + N_TGT) / 4);
    count2_kernel<<<2048, 256, 0, stream>>>(es, ed, cnt_l, cnt_t, NEDGE);
    scan_block_kernel<<<nbL, 256, 0, stream>>>(cnt_l, rowptr_l, bsum_l, N_LIG);
    scan_top_kernel<<<1, 256, 0, stream>>>(bsum_l, nbL);
    add_off_kernel<<<(N_LIG + 255) / 256, 256, 0, stream>>>(rowptr_l, bsum_l, N_LIG, NEDGE);
    scan_block_kernel<<<nbT, 256, 0, stream>>>(cnt_t, rowptr_t, bsum_t, N_TGT);
    scan_top_kernel<<<1, 256, 0, stream>>>(bsum_t, nbT);
    add_off_kernel<<<(N_TGT + 255) / 256, 256, 0, stream>>>(rowptr_t, bsum_t, N_TGT, NEDGE);
    copy_i_kernel<<<(N_LIG + 255) / 256, 256, 0, stream>>>(rowptr_l, cur_l, N_LIG);
    copy_i_kernel<<<(N_TGT + 255) / 256, 256, 0, stream>>>(rowptr_t, cur_t, N_TGT);
    fill_csr_kernel<<<2048, 256, 0, stream>>>(es, ed, cur_l, cur_t, nbr_l, nbr_t, NEDGE);

    // 3. two conv layers (gather-mean + GEMM)
    const float* Wf[2] = {W1f, W2f};
    const float* bf[2] = {b1f, b2f};
    const float* Wr[2] = {W1r, W2r};
    const float* br[2] = {b1r, b2r};
    for (int layer = 0; layer < 2; ++layer) {
        gather_mean_kernel<<<(N_TGT * 64 + 255) / 256, 256, 0, stream>>>(L0, rowptr_t, nbr_t, T1, N_TGT);
        gather_mean_kernel<<<(N_LIG * 64 + 255) / 256, 256, 0, stream>>>(T0, rowptr_l, nbr_l, L1, N_LIG);
        linear128<<<tgtBlocks, 256, 0, stream>>>(T1, Wf[layer], bf[layer], T0, N_TGT, H, 1);
        linear128<<<ligBlocks, 256, 0, stream>>>(L1, Wr[layer], br[layer], L0, N_LIG, H, 1);
    }

    // 4. edge-MLP factorization: A = h_lig @ Wp1_top; B = h_tgt @ Wp1_bot + bp1
    linear128<<<ligBlocks, 256, 0, stream>>>(L0, Wp1, nullptr, L1, N_LIG, H, 0);
    linear128<<<tgtBlocks, 256, 0, stream>>>(T0, Wp1 + 128 * H, bp1, T1, N_TGT, H, 0);

    // 5. per-edge: pred = relu(A[s]+B[d]) . Wp2 + bp2
    edge_mlp_kernel<<<(int)(((long)NEDGE * 16 + 255) / 256), 256, 0, stream>>>(
        L1, T1, es, ed, Wp2, bp2, out, NEDGE);
}

// Round 4
// 767.765 us; speedup vs baseline: 9.8454x; 1.5910x over previous
//
#include <hip/hip_runtime.h>
#include <hip/hip_bf16.h>

#define N_LIG 100000
#define N_TGT 20000
#define NEDGE 1000000
#define H 128

typedef __attribute__((ext_vector_type(8))) short short8v;
typedef __attribute__((ext_vector_type(4))) float f32x4;

// ---- bf16 helpers (manual RTN-even, bit ops only) ----
__device__ __forceinline__ unsigned short f2bs(float f) {
    unsigned int u = __float_as_uint(f);
    u += 0x7fff + ((u >> 16) & 1);
    return (unsigned short)(u >> 16);
}
__device__ __forceinline__ float bs2f(unsigned int s) {
    return __uint_as_float(s << 16);
}

// ---------------- zero fill ----------------
__global__ void zero_f4(float4* __restrict__ p, long n4) {
    long i = (long)blockIdx.x * blockDim.x + threadIdx.x;
    long stride = (long)gridDim.x * blockDim.x;
    for (; i < n4; i += stride) p[i] = make_float4(0.f, 0.f, 0.f, 0.f);
}

// ---------------- fp32 -> bf16 convert ----------------
__global__ void cvt_bf16(const float4* __restrict__ in, ushort4* __restrict__ out, long n4) {
    long i = (long)blockIdx.x * blockDim.x + threadIdx.x;
    long stride = (long)gridDim.x * blockDim.x;
    for (; i < n4; i += stride) {
        float4 v = in[i];
        ushort4 o;
        o.x = f2bs(v.x); o.y = f2bs(v.y); o.z = f2bs(v.z); o.w = f2bs(v.w);
        out[i] = o;
    }
}

// ---------------- weight transpose+convert: W[K][128] f32 -> Wt[128][K] bf16 ----------------
__global__ void transpose_w(const float* __restrict__ W, unsigned short* __restrict__ Wt, int K) {
    int idx = blockIdx.x * blockDim.x + threadIdx.x;
    if (idx >= K * 128) return;
    int k = idx >> 7, c = idx & 127;
    Wt[(size_t)c * K + k] = f2bs(W[idx]);
}

// ---------------- ligand embed: K=4, bf16 out ----------------
__global__ void lin4_bf16(const float* __restrict__ X, const float* __restrict__ W,
                          const float* __restrict__ b, unsigned short* __restrict__ Y, int N) {
    int idx = blockIdx.x * blockDim.x + threadIdx.x;  // N*16, 8 cols each
    if (idx >= N * 16) return;
    int r = idx >> 4;
    int c = (idx & 15) * 8;
    float x0 = X[r * 4 + 0], x1 = X[r * 4 + 1], x2 = X[r * 4 + 2], x3 = X[r * 4 + 3];
    unsigned int o[4];
#pragma unroll
    for (int p = 0; p < 4; ++p) {
        float v0 = b[c + 2 * p] + x0 * W[c + 2 * p] + x1 * W[H + c + 2 * p] +
                   x2 * W[2 * H + c + 2 * p] + x3 * W[3 * H + c + 2 * p];
        float v1 = b[c + 2 * p + 1] + x0 * W[c + 2 * p + 1] + x1 * W[H + c + 2 * p + 1] +
                   x2 * W[2 * H + c + 2 * p + 1] + x3 * W[3 * H + c + 2 * p + 1];
        o[p] = (unsigned int)f2bs(v0) | ((unsigned int)f2bs(v1) << 16);
    }
    uint4 u = make_uint4(o[0], o[1], o[2], o[3]);
    *(uint4*)&Y[(size_t)r * H + c] = u;
}

// ---------------- MFMA GEMM: act(X_bf16[N][K] @ W + bias) -> Y (bf16) or Yf (fp32) ----------------
// Wt: [128][K] bf16 (W pre-transposed). 64 rows/block, 4 waves x 16 rows x 128 cols.
__launch_bounds__(256)
__global__ void gemm_bf16(const unsigned short* __restrict__ X,
                          const unsigned short* __restrict__ Wt,
                          const float* __restrict__ bias,
                          unsigned short* __restrict__ Y,
                          float* __restrict__ Yf,
                          int N, int K, int do_relu) {
    __shared__ unsigned short Ws[128 * 128];  // 32 KB, rows of 256 B, XOR-swizzled
    const int t = threadIdx.x;
    const int wv = t >> 6;
    const int lane = t & 63;
    const int lr = lane & 15;   // A row within tile / B,D col within tile
    const int kb = lane >> 4;   // k-block
    const int row0 = blockIdx.x * 64 + wv * 16;

    f32x4 acc[8];
#pragma unroll
    for (int i = 0; i < 8; ++i) acc[i] = (f32x4){0.f, 0.f, 0.f, 0.f};

    int arow = row0 + lr;
    if (arow >= N) arow = N - 1;  // clamp (results masked in epilogue)
    const unsigned short* xrow = X + (size_t)arow * K;

    const int nch = K >> 7;
    for (int kc = 0; kc < nch; ++kc) {
        if (kc) __syncthreads();
        // stage Wt chunk: 128 rows x 256 B = 32 KB; 2048 x 16 B; 8 per thread
#pragma unroll
        for (int i = 0; i < 8; ++i) {
            int li = t + i * 256;
            int r = li >> 4;
            int cb = (li & 15) << 4;
            int4 v = *(const int4*)(Wt + (size_t)r * K + (kc << 7) + (cb >> 1));
            *(int4*)((char*)Ws + r * 256 + (cb ^ ((r & 7) << 4))) = v;
        }
        // A-frags straight from global (16 rows x 64 B, coalesced)
        short8v a[4];
#pragma unroll
        for (int ks = 0; ks < 4; ++ks)
            a[ks] = *(const short8v*)(xrow + (kc << 7) + ks * 32 + kb * 8);
        __syncthreads();
#pragma unroll
        for (int ks = 0; ks < 4; ++ks) {
            int ofs = ks * 64 + kb * 16;
#pragma unroll
            for (int ct = 0; ct < 8; ++ct) {
                int c = ct * 16 + lr;
                short8v b = *(const short8v*)((const char*)Ws + c * 256 + (ofs ^ ((c & 7) << 4)));
                acc[ct] = __builtin_amdgcn_mfma_f32_16x16x32_bf16(a[ks], b, acc[ct], 0, 0, 0);
            }
        }
    }
    // epilogue: D[i][j]: j = ct*16+lr, i = kb*4+r
#pragma unroll
    for (int ct = 0; ct < 8; ++ct) {
        int col = ct * 16 + lr;
        float bv = bias ? bias[col] : 0.f;
#pragma unroll
        for (int r = 0; r < 4; ++r) {
            int grow = row0 + kb * 4 + r;
            if (grow < N) {
                float v = acc[ct][r] + bv;
                if (do_relu) v = fmaxf(v, 0.f);
                if (Yf) Yf[(size_t)grow * H + col] = v;
                else    Y[(size_t)grow * H + col] = f2bs(v);
            }
        }
    }
}

// ---------------- CSR build ----------------
__global__ void count2_kernel(const int* __restrict__ es, const int* __restrict__ ed,
                              int* __restrict__ cl, int* __restrict__ ct, int E) {
    int i = blockIdx.x * blockDim.x + threadIdx.x;
    int stride = gridDim.x * blockDim.x;
    for (; i < E; i += stride) {
        atomicAdd(&cl[es[i]], 1);
        atomicAdd(&ct[ed[i]], 1);
    }
}

__global__ void scan_block_kernel(const int* __restrict__ in, int* __restrict__ out,
                                  int* __restrict__ bsum, int n) {
    __shared__ int ts[256];
    int t = threadIdx.x;
    int base = blockIdx.x * 1024 + t * 4;
    int v[4];
    int s = 0;
#pragma unroll
    for (int i = 0; i < 4; i++) {
        v[i] = (base + i < n) ? in[base + i] : 0;
        s += v[i];
    }
    ts[t] = s;
    __syncthreads();
    for (int ofs = 1; ofs < 256; ofs <<= 1) {
        int x = (t >= ofs) ? ts[t - ofs] : 0;
        __syncthreads();
        ts[t] += x;
        __syncthreads();
    }
    int run = (t == 0) ? 0 : ts[t - 1];
    if (t == 255) bsum[blockIdx.x] = ts[255];
#pragma unroll
    for (int i = 0; i < 4; i++) {
        if (base + i < n) out[base + i] = run;
        run += v[i];
    }
}

__global__ void scan_top_kernel(int* __restrict__ bsum, int nb) {
    __shared__ int ts[256];
    int t = threadIdx.x;
    ts[t] = (t < nb) ? bsum[t] : 0;
    __syncthreads();
    for (int ofs = 1; ofs < 256; ofs <<= 1) {
        int x = (t >= ofs) ? ts[t - ofs] : 0;
        __syncthreads();
        ts[t] += x;
        __syncthreads();
    }
    int excl = (t == 0) ? 0 : ts[t - 1];
    if (t < nb) bsum[t] = excl;
}

__global__ void add_off_kernel(int* __restrict__ out, const int* __restrict__ bsum, int n, int total) {
    int i = blockIdx.x * blockDim.x + threadIdx.x;
    if (i < n) out[i] += bsum[i >> 10];
    if (i == 0) out[n] = total;
}

__global__ void copy_i_kernel(const int* __restrict__ in, int* __restrict__ out, int n) {
    int i = blockIdx.x * blockDim.x + threadIdx.x;
    if (i < n) out[i] = in[i];
}

__global__ void fill_csr_kernel(const int* __restrict__ es, const int* __restrict__ ed,
                                int* __restrict__ cur_l, int* __restrict__ cur_t,
                                int* __restrict__ nbr_l, int* __restrict__ nbr_t, int E) {
    int i = blockIdx.x * blockDim.x + threadIdx.x;
    int stride = gridDim.x * blockDim.x;
    for (; i < E; i += stride) {
        int s = es[i], d = ed[i];
        nbr_l[atomicAdd(&cur_l[s], 1)] = d;
        nbr_t[atomicAdd(&cur_t[d], 1)] = s;
    }
}

// ---------------- gather-mean (bf16 in/out, fp32 accum): one wave per node ----------------
__launch_bounds__(256)
__global__ void gather_mean_bf16(const unsigned short* __restrict__ feat,
                                 const int* __restrict__ rowptr, const int* __restrict__ nbr,
                                 unsigned short* __restrict__ out, int N) {
    int wid = (blockIdx.x * blockDim.x + threadIdx.x) >> 6;
    if (wid >= N) return;
    int lane = threadIdx.x & 63;
    int beg = rowptr[wid], end = rowptr[wid + 1];
    const unsigned int* f = (const unsigned int*)feat;  // 2 bf16 per uint, lane -> cols 2l,2l+1
    float ax = 0.f, ay = 0.f;
    int j = beg;
    for (; j + 4 <= end; j += 4) {
        unsigned int v0 = f[(size_t)nbr[j] * 64 + lane];
        unsigned int v1 = f[(size_t)nbr[j + 1] * 64 + lane];
        unsigned int v2 = f[(size_t)nbr[j + 2] * 64 + lane];
        unsigned int v3 = f[(size_t)nbr[j + 3] * 64 + lane];
        ax += bs2f(v0 & 0xffff) + bs2f(v1 & 0xffff) + bs2f(v2 & 0xffff) + bs2f(v3 & 0xffff);
        ay += bs2f(v0 >> 16) + bs2f(v1 >> 16) + bs2f(v2 >> 16) + bs2f(v3 >> 16);
    }
    for (; j < end; ++j) {
        unsigned int v = f[(size_t)nbr[j] * 64 + lane];
        ax += bs2f(v & 0xffff);
        ay += bs2f(v >> 16);
    }
    float inv = 1.f / (float)max(end - beg, 1);
    unsigned int o = (unsigned int)f2bs(ax * inv) | ((unsigned int)f2bs(ay * inv) << 16);
    ((unsigned int*)out)[(size_t)wid * 64 + lane] = o;
}

// ---------------- edge MLP (fp32 A,B): pred[e] = relu(A[s]+B[d]) . Wp2 + bp2 ----------------
__global__ void edge_mlp_kernel(const float* __restrict__ A, const float* __restrict__ B,
                                const int* __restrict__ es, const int* __restrict__ ed,
                                const float* __restrict__ Wp2, const float* __restrict__ bp2,
                                float* __restrict__ out, int E) {
    long gid = (long)blockIdx.x * blockDim.x + threadIdx.x;
    long e = gid >> 4;
    if (e >= E) return;
    int l16 = (int)(threadIdx.x & 15);
    int s = es[e], d = ed[e];
    const float4* pa = (const float4*)&A[(size_t)s * H + l16 * 8];
    const float4* pb = (const float4*)&B[(size_t)d * H + l16 * 8];
    const float4* pw = (const float4*)&Wp2[l16 * 8];
    float4 a0 = pa[0], a1 = pa[1];
    float4 b0 = pb[0], b1 = pb[1];
    float4 w0 = pw[0], w1 = pw[1];
    float acc = fmaxf(a0.x + b0.x, 0.f) * w0.x + fmaxf(a0.y + b0.y, 0.f) * w0.y +
                fmaxf(a0.z + b0.z, 0.f) * w0.z + fmaxf(a0.w + b0.w, 0.f) * w0.w +
                fmaxf(a1.x + b1.x, 0.f) * w1.x + fmaxf(a1.y + b1.y, 0.f) * w1.y +
                fmaxf(a1.z + b1.z, 0.f) * w1.z + fmaxf(a1.w + b1.w, 0.f) * w1.w;
    acc += __shfl_xor(acc, 8);
    acc += __shfl_xor(acc, 4);
    acc += __shfl_xor(acc, 2);
    acc += __shfl_xor(acc, 1);
    if (l16 == 0) out[e] = acc + bp2[0];
}

extern "C" void kernel_launch(void* const* d_in, const int* in_sizes, int n_in,
                              void* d_out, int out_size, void* d_ws, size_t ws_size,
                              hipStream_t stream) {
    const float* x_lig = (const float*)d_in[0];
    const float* x_tgt = (const float*)d_in[1];
    const int* es = (const int*)d_in[2];
    const int* ed = (const int*)d_in[3];
    const float* W_lig = (const float*)d_in[4];
    const float* b_lig = (const float*)d_in[5];
    const float* W_tgt = (const float*)d_in[6];
    const float* b_tgt = (const float*)d_in[7];
    const float* W1f = (const float*)d_in[8];
    const float* b1f = (const float*)d_in[9];
    const float* W1r = (const float*)d_in[10];
    const float* b1r = (const float*)d_in[11];
    const float* W2f = (const float*)d_in[12];
    const float* b2f = (const float*)d_in[13];
    const float* W2r = (const float*)d_in[14];
    const float* b2r = (const float*)d_in[15];
    const float* Wp1 = (const float*)d_in[16];
    const float* bp1 = (const float*)d_in[17];
    const float* Wp2 = (const float*)d_in[18];
    const float* bp2 = (const float*)d_in[19];
    float* out = (float*)d_out;

    char* base = (char*)d_ws;
    size_t off = 0;
    auto alloc = [&](size_t bytes) { char* p = base + off; off = (off + bytes + 255) & ~(size_t)255; return p; };
    unsigned short* L0 = (unsigned short*)alloc((size_t)N_LIG * H * 2);
    unsigned short* L1 = (unsigned short*)alloc((size_t)N_LIG * H * 2);
    unsigned short* T0 = (unsigned short*)alloc((size_t)N_TGT * H * 2);
    unsigned short* T1 = (unsigned short*)alloc((size_t)N_TGT * H * 2);
    unsigned short* XT = (unsigned short*)alloc((size_t)N_TGT * 1280 * 2);  // 51.2 MB
    float* Af = (float*)XT;                                                 // alias: XT dead after step 1
    float* Bf = (float*)alloc((size_t)N_TGT * H * 4);
    unsigned short* Wt_tgt = (unsigned short*)alloc((size_t)128 * 1280 * 2);
    unsigned short* Wt1f = (unsigned short*)alloc(128 * 128 * 2);
    unsigned short* Wt1r = (unsigned short*)alloc(128 * 128 * 2);
    unsigned short* Wt2f = (unsigned short*)alloc(128 * 128 * 2);
    unsigned short* Wt2r = (unsigned short*)alloc(128 * 128 * 2);
    unsigned short* WtA = (unsigned short*)alloc(128 * 128 * 2);
    unsigned short* WtB = (unsigned short*)alloc(128 * 128 * 2);
    int* cnt_l = (int*)alloc(N_LIG * 4);
    int* cnt_t = (int*)alloc(N_TGT * 4);
    int* rowptr_l = (int*)alloc((N_LIG + 4) * 4);
    int* rowptr_t = (int*)alloc((N_TGT + 4) * 4);
    int* cur_l = (int*)alloc(N_LIG * 4);
    int* cur_t = (int*)alloc(N_TGT * 4);
    int* bsum_l = (int*)alloc(256 * 4);
    int* bsum_t = (int*)alloc(256 * 4);
    int* nbr_l = (int*)alloc((size_t)NEDGE * 4);
    int* nbr_t = (int*)alloc((size_t)NEDGE * 4);

    const int ligBlocks = (N_LIG + 63) / 64;
    const int tgtBlocks = (N_TGT + 63) / 64;
    const int nbL = (N_LIG + 1023) / 1024;
    const int nbT = (N_TGT + 1023) / 1024;

    // 0. weight prep (transpose + bf16) and x_tgt conversion
    transpose_w<<<(1280 * 128 + 255) / 256, 256, 0, stream>>>(W_tgt, Wt_tgt, 1280);
    transpose_w<<<64, 256, 0, stream>>>(W1f, Wt1f, 128);
    transpose_w<<<64, 256, 0, stream>>>(W1r, Wt1r, 128);
    transpose_w<<<64, 256, 0, stream>>>(W2f, Wt2f, 128);
    transpose_w<<<64, 256, 0, stream>>>(W2r, Wt2r, 128);
    transpose_w<<<64, 256, 0, stream>>>(Wp1, WtA, 128);            // top half rows 0..127
    transpose_w<<<64, 256, 0, stream>>>(Wp1 + 128 * H, WtB, 128);  // bottom half
    cvt_bf16<<<2048, 256, 0, stream>>>((const float4*)x_tgt, (ushort4*)XT, (long)N_TGT * 1280 / 4);

    // 1. node embeddings
    lin4_bf16<<<(N_LIG * 16 + 255) / 256, 256, 0, stream>>>(x_lig, W_lig, b_lig, L0, N_LIG);
    gemm_bf16<<<tgtBlocks, 256, 0, stream>>>(XT, Wt_tgt, b_tgt, T0, nullptr, N_TGT, 1280, 0);

    // 2. CSR build (both directions) — NOTE: cnt_l / cnt_t zeroed SEPARATELY (256B-aligned allocs)
    zero_f4<<<100, 256, 0, stream>>>((float4*)cnt_l, N_LIG / 4);
    zero_f4<<<20, 256, 0, stream>>>((float4*)cnt_t, N_TGT / 4);
    count2_kernel<<<2048, 256, 0, stream>>>(es, ed, cnt_l, cnt_t, NEDGE);
    scan_block_kernel<<<nbL, 256, 0, stream>>>(cnt_l, rowptr_l, bsum_l, N_LIG);
    scan_top_kernel<<<1, 256, 0, stream>>>(bsum_l, nbL);
    add_off_kernel<<<(N_LIG + 255) / 256, 256, 0, stream>>>(rowptr_l, bsum_l, N_LIG, NEDGE);
    scan_block_kernel<<<nbT, 256, 0, stream>>>(cnt_t, rowptr_t, bsum_t, N_TGT);
    scan_top_kernel<<<1, 256, 0, stream>>>(bsum_t, nbT);
    add_off_kernel<<<(N_TGT + 255) / 256, 256, 0, stream>>>(rowptr_t, bsum_t, N_TGT, NEDGE);
    copy_i_kernel<<<(N_LIG + 255) / 256, 256, 0, stream>>>(rowptr_l, cur_l, N_LIG);
    copy_i_kernel<<<(N_TGT + 255) / 256, 256, 0, stream>>>(rowptr_t, cur_t, N_TGT);
    fill_csr_kernel<<<2048, 256, 0, stream>>>(es, ed, cur_l, cur_t, nbr_l, nbr_t, NEDGE);

    // 3. two conv layers (gather-mean + MFMA GEMM)
    const unsigned short* Wtf[2] = {Wt1f, Wt2f};
    const float* bfp[2] = {b1f, b2f};
    const unsigned short* Wtr[2] = {Wt1r, Wt2r};
    const float* brp[2] = {b1r, b2r};
    for (int layer = 0; layer < 2; ++layer) {
        gather_mean_bf16<<<(N_TGT * 64 + 255) / 256, 256, 0, stream>>>(L0, rowptr_t, nbr_t, T1, N_TGT);
        gather_mean_bf16<<<(N_LIG * 64 + 255) / 256, 256, 0, stream>>>(T0, rowptr_l, nbr_l, L1, N_LIG);
        gemm_bf16<<<tgtBlocks, 256, 0, stream>>>(T1, Wtf[layer], bfp[layer], T0, nullptr, N_TGT, 128, 1);
        gemm_bf16<<<ligBlocks, 256, 0, stream>>>(L1, Wtr[layer], brp[layer], L0, nullptr, N_LIG, 128, 1);
    }

    // 4. edge-MLP factorization (fp32 outputs): A = h_lig @ Wp1_top; B = h_tgt @ Wp1_bot + bp1
    gemm_bf16<<<ligBlocks, 256, 0, stream>>>(L0, WtA, nullptr, nullptr, Af, N_LIG, 128, 0);
    gemm_bf16<<<tgtBlocks, 256, 0, stream>>>(T0, WtB, bp1, nullptr, Bf, N_TGT, 128, 0);

    // 5. per-edge: pred = relu(A[s]+B[d]) . Wp2 + bp2
    edge_mlp_kernel<<<(int)(((long)NEDGE * 16 + 255) / 256), 256, 0, stream>>>(
        Af, Bf, es, ed, Wp2, bp2, out, NEDGE);
}

// Round 5
// 661.020 us; speedup vs baseline: 11.4353x; 1.1615x over previous
//
#include <hip/hip_runtime.h>
#include <hip/hip_bf16.h>

#define N_LIG 100000
#define N_TGT 20000
#define NEDGE 1000000
#define H 128
#define NXCD 8
#define PBLK 256  // blocks per partition for count/fill

typedef __attribute__((ext_vector_type(8))) short short8v;
typedef __attribute__((ext_vector_type(4))) float f32x4;

// ---- bf16 helpers (manual RTN-even, bit ops only) ----
__device__ __forceinline__ unsigned short f2bs(float f) {
    unsigned int u = __float_as_uint(f);
    u += 0x7fff + ((u >> 16) & 1);
    return (unsigned short)(u >> 16);
}
__device__ __forceinline__ float bs2f(unsigned int s) {
    return __uint_as_float(s << 16);
}

// ---------------- weight transpose+convert: W[K][128] f32 -> Wt[128][K] bf16 ----------------
__global__ void transpose_w(const float* __restrict__ W, unsigned short* __restrict__ Wt, int K) {
    int idx = blockIdx.x * blockDim.x + threadIdx.x;
    if (idx >= K * 128) return;
    int k = idx >> 7, c = idx & 127;
    Wt[(size_t)c * K + k] = f2bs(W[idx]);
}

// six 128x128 transposes in one launch
struct P6 { const float* w[6]; unsigned short* o[6]; };
__global__ void transpose6(P6 p) {
    int idx = blockIdx.x * blockDim.x + threadIdx.x;  // 6*16384
    int which = idx >> 14;
    int rem = idx & 16383;
    int k = rem >> 7, c = rem & 127;
    p.o[which][(size_t)c * 128 + k] = f2bs(p.w[which][rem]);
}

// ---------------- ligand embed: K=4, bf16 out ----------------
__global__ void lin4_bf16(const float* __restrict__ X, const float* __restrict__ W,
                          const float* __restrict__ b, unsigned short* __restrict__ Y, int N) {
    int idx = blockIdx.x * blockDim.x + threadIdx.x;  // N*16, 8 cols each
    if (idx >= N * 16) return;
    int r = idx >> 4;
    int c = (idx & 15) * 8;
    float x0 = X[r * 4 + 0], x1 = X[r * 4 + 1], x2 = X[r * 4 + 2], x3 = X[r * 4 + 3];
    unsigned int o[4];
#pragma unroll
    for (int p = 0; p < 4; ++p) {
        float v0 = b[c + 2 * p] + x0 * W[c + 2 * p] + x1 * W[H + c + 2 * p] +
                   x2 * W[2 * H + c + 2 * p] + x3 * W[3 * H + c + 2 * p];
        float v1 = b[c + 2 * p + 1] + x0 * W[c + 2 * p + 1] + x1 * W[H + c + 2 * p + 1] +
                   x2 * W[2 * H + c + 2 * p + 1] + x3 * W[3 * H + c + 2 * p + 1];
        o[p] = (unsigned int)f2bs(v0) | ((unsigned int)f2bs(v1) << 16);
    }
    uint4 u = make_uint4(o[0], o[1], o[2], o[3]);
    *(uint4*)&Y[(size_t)r * H + c] = u;
}

// ---------------- MFMA GEMM: act(X[N][K] @ W + bias) -> Y (bf16) or Yf (fp32) ----------------
// Wt: [128][K] bf16. X either bf16 (X) or fp32 (Xf32, converted in-register).
// 64 rows/block, 4 waves x 16 rows x 128 cols.
__launch_bounds__(256)
__global__ void gemm_bf16(const unsigned short* __restrict__ X,
                          const float* __restrict__ Xf32,
                          const unsigned short* __restrict__ Wt,
                          const float* __restrict__ bias,
                          unsigned short* __restrict__ Y,
                          float* __restrict__ Yf,
                          int N, int K, int do_relu) {
    __shared__ unsigned short Ws[128 * 128];  // 32 KB, rows of 256 B, XOR-swizzled
    const int t = threadIdx.x;
    const int wv = t >> 6;
    const int lane = t & 63;
    const int lr = lane & 15;   // A row within tile / B,D col within tile
    const int kb = lane >> 4;   // k-block
    const int row0 = blockIdx.x * 64 + wv * 16;

    f32x4 acc[8];
#pragma unroll
    for (int i = 0; i < 8; ++i) acc[i] = (f32x4){0.f, 0.f, 0.f, 0.f};

    int arow = row0 + lr;
    if (arow >= N) arow = N - 1;  // clamp (results masked in epilogue)
    const unsigned short* xrow = X ? X + (size_t)arow * K : nullptr;
    const float* xrowf = Xf32 ? Xf32 + (size_t)arow * K : nullptr;

    const int nch = K >> 7;
    for (int kc = 0; kc < nch; ++kc) {
        if (kc) __syncthreads();
        // stage Wt chunk: 128 rows x 256 B = 32 KB; 2048 x 16 B; 8 per thread
#pragma unroll
        for (int i = 0; i < 8; ++i) {
            int li = t + i * 256;
            int r = li >> 4;
            int cb = (li & 15) << 4;
            int4 v = *(const int4*)(Wt + (size_t)r * K + (kc << 7) + (cb >> 1));
            *(int4*)((char*)Ws + r * 256 + (cb ^ ((r & 7) << 4))) = v;
        }
        // A-frags straight from global (16 rows x 64 B, coalesced)
        short8v a[4];
        if (xrow) {
#pragma unroll
            for (int ks = 0; ks < 4; ++ks)
                a[ks] = *(const short8v*)(xrow + (kc << 7) + ks * 32 + kb * 8);
        } else {
#pragma unroll
            for (int ks = 0; ks < 4; ++ks) {
                const float* p = xrowf + (kc << 7) + ks * 32 + kb * 8;
                float4 f0 = *(const float4*)p;
                float4 f1 = *(const float4*)(p + 4);
                short8v av;
                av[0] = (short)f2bs(f0.x); av[1] = (short)f2bs(f0.y);
                av[2] = (short)f2bs(f0.z); av[3] = (short)f2bs(f0.w);
                av[4] = (short)f2bs(f1.x); av[5] = (short)f2bs(f1.y);
                av[6] = (short)f2bs(f1.z); av[7] = (short)f2bs(f1.w);
                a[ks] = av;
            }
        }
        __syncthreads();
#pragma unroll
        for (int ks = 0; ks < 4; ++ks) {
            int ofs = ks * 64 + kb * 16;
#pragma unroll
            for (int ct = 0; ct < 8; ++ct) {
                int c = ct * 16 + lr;
                short8v b = *(const short8v*)((const char*)Ws + c * 256 + (ofs ^ ((c & 7) << 4)));
                acc[ct] = __builtin_amdgcn_mfma_f32_16x16x32_bf16(a[ks], b, acc[ct], 0, 0, 0);
            }
        }
    }
    // epilogue: D[i][j]: j = ct*16+lr, i = kb*4+r
#pragma unroll
    for (int ct = 0; ct < 8; ++ct) {
        int col = ct * 16 + lr;
        float bv = bias ? bias[col] : 0.f;
#pragma unroll
        for (int r = 0; r < 4; ++r) {
            int grow = row0 + kb * 4 + r;
            if (grow < N) {
                float v = acc[ct][r] + bv;
                if (do_relu) v = fmaxf(v, 0.f);
                if (Yf) Yf[(size_t)grow * H + col] = v;
                else    Y[(size_t)grow * H + col] = f2bs(v);
            }
        }
    }
}

// ---------------- CSR build (XCD-partitioned scatter) ----------------
__global__ void zero2_kernel(int* __restrict__ a, int na, int* __restrict__ b, int nb) {
    int i = blockIdx.x * blockDim.x + threadIdx.x;
    int stride = gridDim.x * blockDim.x;
    for (int j = i; j < na; j += stride) a[j] = 0;
    for (int j = i; j < nb; j += stride) b[j] = 0;
}

// partition p = blockIdx%8 owns node ranges [p*RL,(p+1)*RL) / [p*RT,(p+1)*RT);
// its PBLK blocks cover all edges; only in-range nodes are counted -> XCD-local atomics.
__global__ void count_part(const int* __restrict__ es, const int* __restrict__ ed,
                           int* __restrict__ cl, int* __restrict__ ct, int E) {
    const int p = blockIdx.x & (NXCD - 1);
    const int pblk = blockIdx.x >> 3;
    const int RL = (N_LIG + NXCD - 1) / NXCD;
    const int RT = (N_TGT + NXCD - 1) / NXCD;
    const int lo_s = p * RL, hi_s = lo_s + RL;
    const int lo_d = p * RT, hi_d = lo_d + RT;
    for (int e = pblk * 256 + threadIdx.x; e < E; e += PBLK * 256) {
        int s = es[e], d = ed[e];
        if (s >= lo_s && s < hi_s) atomicAdd(&cl[s], 1);
        if (d >= lo_d && d < hi_d) atomicAdd(&ct[d], 1);
    }
}

__global__ void fill_part(const int* __restrict__ es, const int* __restrict__ ed,
                          int* __restrict__ cur_l, int* __restrict__ cur_t,
                          int* __restrict__ nbr_l, int* __restrict__ nbr_t, int E) {
    const int p = blockIdx.x & (NXCD - 1);
    const int pblk = blockIdx.x >> 3;
    const int RL = (N_LIG + NXCD - 1) / NXCD;
    const int RT = (N_TGT + NXCD - 1) / NXCD;
    const int lo_s = p * RL, hi_s = lo_s + RL;
    const int lo_d = p * RT, hi_d = lo_d + RT;
    for (int e = pblk * 256 + threadIdx.x; e < E; e += PBLK * 256) {
        int s = es[e], d = ed[e];
        if (s >= lo_s && s < hi_s) nbr_l[atomicAdd(&cur_l[s], 1)] = d;
        if (d >= lo_d && d < hi_d) nbr_t[atomicAdd(&cur_t[d], 1)] = s;
    }
}

// merged hierarchical exclusive scan over the two count arrays
__global__ void scan_block2(const int* __restrict__ in_l, int* __restrict__ out_l,
                            int* __restrict__ bs_l, int nL, int nbL,
                            const int* __restrict__ in_t, int* __restrict__ out_t,
                            int* __restrict__ bs_t, int nT) {
    __shared__ int ts[256];
    const int* in; int* out; int* bsum; int n; int bi;
    if ((int)blockIdx.x < nbL) { in = in_l; out = out_l; bsum = bs_l; n = nL; bi = blockIdx.x; }
    else { in = in_t; out = out_t; bsum = bs_t; n = nT; bi = blockIdx.x - nbL; }
    int t = threadIdx.x;
    int base = bi * 1024 + t * 4;
    int v[4];
    int s = 0;
#pragma unroll
    for (int i = 0; i < 4; i++) {
        v[i] = (base + i < n) ? in[base + i] : 0;
        s += v[i];
    }
    ts[t] = s;
    __syncthreads();
    for (int ofs = 1; ofs < 256; ofs <<= 1) {
        int x = (t >= ofs) ? ts[t - ofs] : 0;
        __syncthreads();
        ts[t] += x;
        __syncthreads();
    }
    int run = (t == 0) ? 0 : ts[t - 1];
    if (t == 255) bsum[bi] = ts[255];
#pragma unroll
    for (int i = 0; i < 4; i++) {
        if (base + i < n) out[base + i] = run;
        run += v[i];
    }
}

__global__ void scan_top2(int* __restrict__ bs_l, int nbL, int* __restrict__ bs_t, int nbT) {
    __shared__ int ts[256];
    int* bsum = (blockIdx.x == 0) ? bs_l : bs_t;
    int nb = (blockIdx.x == 0) ? nbL : nbT;
    int t = threadIdx.x;
    ts[t] = (t < nb) ? bsum[t] : 0;
    __syncthreads();
    for (int ofs = 1; ofs < 256; ofs <<= 1) {
        int x = (t >= ofs) ? ts[t - ofs] : 0;
        __syncthreads();
        ts[t] += x;
        __syncthreads();
    }
    int excl = (t == 0) ? 0 : ts[t - 1];
    if (t < nb) bsum[t] = excl;
}

// adds block offsets, writes rowptr AND cursor copies, sets end sentinels
__global__ void add_off2(int* __restrict__ rp_l, const int* __restrict__ bs_l, int* __restrict__ cur_l,
                         int* __restrict__ rp_t, const int* __restrict__ bs_t, int* __restrict__ cur_t) {
    int i = blockIdx.x * blockDim.x + threadIdx.x;
    if (i < N_LIG) {
        int v = rp_l[i] + bs_l[i >> 10];
        rp_l[i] = v;
        cur_l[i] = v;
        if (i == 0) rp_l[N_LIG] = NEDGE;
    } else if (i < N_LIG + N_TGT) {
        int j = i - N_LIG;
        int v = rp_t[j] + bs_t[j >> 10];
        rp_t[j] = v;
        cur_t[j] = v;
        if (j == 0) rp_t[N_TGT] = NEDGE;
    }
}

// ---------------- gather-mean (bf16 in/out, fp32 accum): one wave per node ----------------
__launch_bounds__(256)
__global__ void gather_mean_bf16(const unsigned short* __restrict__ feat,
                                 const int* __restrict__ rowptr, const int* __restrict__ nbr,
                                 unsigned short* __restrict__ out, int N) {
    int wid = (blockIdx.x * blockDim.x + threadIdx.x) >> 6;
    if (wid >= N) return;
    int lane = threadIdx.x & 63;
    int beg = rowptr[wid], end = rowptr[wid + 1];
    const unsigned int* f = (const unsigned int*)feat;  // 2 bf16 per uint
    float ax = 0.f, ay = 0.f;
    int j = beg;
    for (; j + 4 <= end; j += 4) {
        unsigned int v0 = f[(size_t)nbr[j] * 64 + lane];
        unsigned int v1 = f[(size_t)nbr[j + 1] * 64 + lane];
        unsigned int v2 = f[(size_t)nbr[j + 2] * 64 + lane];
        unsigned int v3 = f[(size_t)nbr[j + 3] * 64 + lane];
        ax += bs2f(v0 & 0xffff) + bs2f(v1 & 0xffff) + bs2f(v2 & 0xffff) + bs2f(v3 & 0xffff);
        ay += bs2f(v0 >> 16) + bs2f(v1 >> 16) + bs2f(v2 >> 16) + bs2f(v3 >> 16);
    }
    for (; j < end; ++j) {
        unsigned int v = f[(size_t)nbr[j] * 64 + lane];
        ax += bs2f(v & 0xffff);
        ay += bs2f(v >> 16);
    }
    float inv = 1.f / (float)max(end - beg, 1);
    unsigned int o = (unsigned int)f2bs(ax * inv) | ((unsigned int)f2bs(ay * inv) << 16);
    ((unsigned int*)out)[(size_t)wid * 64 + lane] = o;
}

// ---------------- edge MLP (fp32 A,B): pred[e] = relu(A[s]+B[d]) . Wp2 + bp2 ----------------
__global__ void edge_mlp_kernel(const float* __restrict__ A, const float* __restrict__ B,
                                const int* __restrict__ es, const int* __restrict__ ed,
                                const float* __restrict__ Wp2, const float* __restrict__ bp2,
                                float* __restrict__ out, int E) {
    long gid = (long)blockIdx.x * blockDim.x + threadIdx.x;
    long e = gid >> 4;
    if (e >= E) return;
    int l16 = (int)(threadIdx.x & 15);
    int s = es[e], d = ed[e];
    const float4* pa = (const float4*)&A[(size_t)s * H + l16 * 8];
    const float4* pb = (const float4*)&B[(size_t)d * H + l16 * 8];
    const float4* pw = (const float4*)&Wp2[l16 * 8];
    float4 a0 = pa[0], a1 = pa[1];
    float4 b0 = pb[0], b1 = pb[1];
    float4 w0 = pw[0], w1 = pw[1];
    float acc = fmaxf(a0.x + b0.x, 0.f) * w0.x + fmaxf(a0.y + b0.y, 0.f) * w0.y +
                fmaxf(a0.z + b0.z, 0.f) * w0.z + fmaxf(a0.w + b0.w, 0.f) * w0.w +
                fmaxf(a1.x + b1.x, 0.f) * w1.x + fmaxf(a1.y + b1.y, 0.f) * w1.y +
                fmaxf(a1.z + b1.z, 0.f) * w1.z + fmaxf(a1.w + b1.w, 0.f) * w1.w;
    acc += __shfl_xor(acc, 8);
    acc += __shfl_xor(acc, 4);
    acc += __shfl_xor(acc, 2);
    acc += __shfl_xor(acc, 1);
    if (l16 == 0) out[e] = acc + bp2[0];
}

extern "C" void kernel_launch(void* const* d_in, const int* in_sizes, int n_in,
                              void* d_out, int out_size, void* d_ws, size_t ws_size,
                              hipStream_t stream) {
    const float* x_lig = (const float*)d_in[0];
    const float* x_tgt = (const float*)d_in[1];
    const int* es = (const int*)d_in[2];
    const int* ed = (const int*)d_in[3];
    const float* W_lig = (const float*)d_in[4];
    const float* b_lig = (const float*)d_in[5];
    const float* W_tgt = (const float*)d_in[6];
    const float* b_tgt = (const float*)d_in[7];
    const float* W1f = (const float*)d_in[8];
    const float* b1f = (const float*)d_in[9];
    const float* W1r = (const float*)d_in[10];
    const float* b1r = (const float*)d_in[11];
    const float* W2f = (const float*)d_in[12];
    const float* b2f = (const float*)d_in[13];
    const float* W2r = (const float*)d_in[14];
    const float* b2r = (const float*)d_in[15];
    const float* Wp1 = (const float*)d_in[16];
    const float* bp1 = (const float*)d_in[17];
    const float* Wp2 = (const float*)d_in[18];
    const float* bp2 = (const float*)d_in[19];
    float* out = (float*)d_out;

    char* base = (char*)d_ws;
    size_t off = 0;
    auto alloc = [&](size_t bytes) { char* p = base + off; off = (off + bytes + 255) & ~(size_t)255; return p; };
    unsigned short* L0 = (unsigned short*)alloc((size_t)N_LIG * H * 2);
    unsigned short* L1 = (unsigned short*)alloc((size_t)N_LIG * H * 2);
    unsigned short* T0 = (unsigned short*)alloc((size_t)N_TGT * H * 2);
    unsigned short* T1 = (unsigned short*)alloc((size_t)N_TGT * H * 2);
    float* Af = (float*)alloc((size_t)N_LIG * H * 4);   // 51.2 MB
    float* Bf = (float*)alloc((size_t)N_TGT * H * 4);   // 10.2 MB
    unsigned short* Wt_tgt = (unsigned short*)alloc((size_t)128 * 1280 * 2);
    unsigned short* Wt1f = (unsigned short*)alloc(128 * 128 * 2);
    unsigned short* Wt1r = (unsigned short*)alloc(128 * 128 * 2);
    unsigned short* Wt2f = (unsigned short*)alloc(128 * 128 * 2);
    unsigned short* Wt2r = (unsigned short*)alloc(128 * 128 * 2);
    unsigned short* WtA = (unsigned short*)alloc(128 * 128 * 2);
    unsigned short* WtB = (unsigned short*)alloc(128 * 128 * 2);
    int* cnt_l = (int*)alloc(N_LIG * 4);
    int* cnt_t = (int*)alloc(N_TGT * 4);
    int* rowptr_l = (int*)alloc((N_LIG + 4) * 4);
    int* rowptr_t = (int*)alloc((N_TGT + 4) * 4);
    int* cur_l = (int*)alloc(N_LIG * 4);
    int* cur_t = (int*)alloc(N_TGT * 4);
    int* bsum_l = (int*)alloc(256 * 4);
    int* bsum_t = (int*)alloc(256 * 4);
    int* nbr_l = (int*)alloc((size_t)NEDGE * 4);
    int* nbr_t = (int*)alloc((size_t)NEDGE * 4);

    const int ligBlocks = (N_LIG + 63) / 64;
    const int tgtBlocks = (N_TGT + 63) / 64;
    const int nbL = (N_LIG + 1023) / 1024;   // 98
    const int nbT = (N_TGT + 1023) / 1024;   // 20

    // 0. weight prep (transpose + bf16)
    transpose_w<<<(1280 * 128 + 255) / 256, 256, 0, stream>>>(W_tgt, Wt_tgt, 1280);
    P6 p6;
    p6.w[0] = W1f; p6.o[0] = Wt1f;
    p6.w[1] = W1r; p6.o[1] = Wt1r;
    p6.w[2] = W2f; p6.o[2] = Wt2f;
    p6.w[3] = W2r; p6.o[3] = Wt2r;
    p6.w[4] = Wp1;           p6.o[4] = WtA;   // top half rows 0..127
    p6.w[5] = Wp1 + 128 * H; p6.o[5] = WtB;   // bottom half
    transpose6<<<6 * 64, 256, 0, stream>>>(p6);

    // 1. node embeddings (x_tgt converted to bf16 in-register inside the GEMM)
    lin4_bf16<<<(N_LIG * 16 + 255) / 256, 256, 0, stream>>>(x_lig, W_lig, b_lig, L0, N_LIG);
    gemm_bf16<<<tgtBlocks, 256, 0, stream>>>(nullptr, x_tgt, Wt_tgt, b_tgt, T0, nullptr, N_TGT, 1280, 0);

    // 2. CSR build, XCD-partitioned
    zero2_kernel<<<120, 256, 0, stream>>>(cnt_l, N_LIG, cnt_t, N_TGT);
    count_part<<<NXCD * PBLK, 256, 0, stream>>>(es, ed, cnt_l, cnt_t, NEDGE);
    scan_block2<<<nbL + nbT, 256, 0, stream>>>(cnt_l, rowptr_l, bsum_l, N_LIG, nbL,
                                               cnt_t, rowptr_t, bsum_t, N_TGT);
    scan_top2<<<2, 256, 0, stream>>>(bsum_l, nbL, bsum_t, nbT);
    add_off2<<<(N_LIG + N_TGT + 255) / 256, 256, 0, stream>>>(rowptr_l, bsum_l, cur_l,
                                                              rowptr_t, bsum_t, cur_t);
    fill_part<<<NXCD * PBLK, 256, 0, stream>>>(es, ed, cur_l, cur_t, nbr_l, nbr_t, NEDGE);

    // 3. two conv layers (gather-mean + MFMA GEMM)
    const unsigned short* Wtf[2] = {Wt1f, Wt2f};
    const float* bfp[2] = {b1f, b2f};
    const unsigned short* Wtr[2] = {Wt1r, Wt2r};
    const float* brp[2] = {b1r, b2r};
    for (int layer = 0; layer < 2; ++layer) {
        gather_mean_bf16<<<(N_TGT * 64 + 255) / 256, 256, 0, stream>>>(L0, rowptr_t, nbr_t, T1, N_TGT);
        gather_mean_bf16<<<(N_LIG * 64 + 255) / 256, 256, 0, stream>>>(T0, rowptr_l, nbr_l, L1, N_LIG);
        gemm_bf16<<<tgtBlocks, 256, 0, stream>>>(T1, nullptr, Wtf[layer], bfp[layer], T0, nullptr, N_TGT, 128, 1);
        gemm_bf16<<<ligBlocks, 256, 0, stream>>>(L1, nullptr, Wtr[layer], brp[layer], L0, nullptr, N_LIG, 128, 1);
    }

    // 4. edge-MLP factorization (fp32 outputs): A = h_lig @ Wp1_top; B = h_tgt @ Wp1_bot + bp1
    gemm_bf16<<<ligBlocks, 256, 0, stream>>>(L0, nullptr, WtA, nullptr, nullptr, Af, N_LIG, 128, 0);
    gemm_bf16<<<tgtBlocks, 256, 0, stream>>>(T0, nullptr, WtB, bp1, nullptr, Bf, N_TGT, 128, 0);

    // 5. per-edge: pred = relu(A[s]+B[d]) . Wp2 + bp2
    edge_mlp_kernel<<<(int)(((long)NEDGE * 16 + 255) / 256), 256, 0, stream>>>(
        Af, Bf, es, ed, Wp2, bp2, out, NEDGE);
}

// Round 6
// 607.807 us; speedup vs baseline: 12.4364x; 1.0875x over previous
//
#include <hip/hip_runtime.h>
#include <hip/hip_bf16.h>

#define N_LIG 100000
#define N_TGT 20000
#define NEDGE 1000000
#define H 128
#define NXCD 8
#define PBLK 256  // blocks per partition for count/fill

typedef __attribute__((ext_vector_type(8))) short short8v;
typedef __attribute__((ext_vector_type(4))) float f32x4;

// ---- bf16 helpers (manual RTN-even, bit ops only) ----
__device__ __forceinline__ unsigned short f2bs(float f) {
    unsigned int u = __float_as_uint(f);
    u += 0x7fff + ((u >> 16) & 1);
    return (unsigned short)(u >> 16);
}
__device__ __forceinline__ float bs2f(unsigned int s) {
    return __uint_as_float(s << 16);
}

// ---------------- weight transpose+convert: W[K][128] f32 -> Wt[128][K] bf16 ----------------
__global__ void transpose_w(const float* __restrict__ W, unsigned short* __restrict__ Wt, int K) {
    int idx = blockIdx.x * blockDim.x + threadIdx.x;
    if (idx >= K * 128) return;
    int k = idx >> 7, c = idx & 127;
    Wt[(size_t)c * K + k] = f2bs(W[idx]);
}

// six 128x128 transposes in one launch
struct P6 { const float* w[6]; unsigned short* o[6]; };
__global__ void transpose6(P6 p) {
    int idx = blockIdx.x * blockDim.x + threadIdx.x;  // 6*16384
    int which = idx >> 14;
    int rem = idx & 16383;
    int k = rem >> 7, c = rem & 127;
    p.o[which][(size_t)c * 128 + k] = f2bs(p.w[which][rem]);
}

// ---------------- ligand embed: K=4, bf16 out ----------------
__global__ void lin4_bf16(const float* __restrict__ X, const float* __restrict__ W,
                          const float* __restrict__ b, unsigned short* __restrict__ Y, int N) {
    int idx = blockIdx.x * blockDim.x + threadIdx.x;  // N*16, 8 cols each
    if (idx >= N * 16) return;
    int r = idx >> 4;
    int c = (idx & 15) * 8;
    float x0 = X[r * 4 + 0], x1 = X[r * 4 + 1], x2 = X[r * 4 + 2], x3 = X[r * 4 + 3];
    unsigned int o[4];
#pragma unroll
    for (int p = 0; p < 4; ++p) {
        float v0 = b[c + 2 * p] + x0 * W[c + 2 * p] + x1 * W[H + c + 2 * p] +
                   x2 * W[2 * H + c + 2 * p] + x3 * W[3 * H + c + 2 * p];
        float v1 = b[c + 2 * p + 1] + x0 * W[c + 2 * p + 1] + x1 * W[H + c + 2 * p + 1] +
                   x2 * W[2 * H + c + 2 * p + 1] + x3 * W[3 * H + c + 2 * p + 1];
        o[p] = (unsigned int)f2bs(v0) | ((unsigned int)f2bs(v1) << 16);
    }
    uint4 u = make_uint4(o[0], o[1], o[2], o[3]);
    *(uint4*)&Y[(size_t)r * H + c] = u;
}

// ---------------- MFMA GEMM: act(X[N][K] @ W + bias) -> Y (bf16) or Yf (fp32) ----------------
// Wt: [128][K] bf16. X either bf16 (X) or fp32 (Xf32, converted in-register).
// 64 rows/block, 4 waves x 16 rows x 128 cols.
__launch_bounds__(256)
__global__ void gemm_bf16(const unsigned short* __restrict__ X,
                          const float* __restrict__ Xf32,
                          const unsigned short* __restrict__ Wt,
                          const float* __restrict__ bias,
                          unsigned short* __restrict__ Y,
                          float* __restrict__ Yf,
                          int N, int K, int do_relu) {
    __shared__ unsigned short Ws[128 * 128];  // 32 KB, rows of 256 B, XOR-swizzled
    const int t = threadIdx.x;
    const int wv = t >> 6;
    const int lane = t & 63;
    const int lr = lane & 15;   // A row within tile / B,D col within tile
    const int kb = lane >> 4;   // k-block
    const int row0 = blockIdx.x * 64 + wv * 16;

    f32x4 acc[8];
#pragma unroll
    for (int i = 0; i < 8; ++i) acc[i] = (f32x4){0.f, 0.f, 0.f, 0.f};

    int arow = row0 + lr;
    if (arow >= N) arow = N - 1;  // clamp (results masked in epilogue)
    const unsigned short* xrow = X ? X + (size_t)arow * K : nullptr;
    const float* xrowf = Xf32 ? Xf32 + (size_t)arow * K : nullptr;

    const int nch = K >> 7;
    for (int kc = 0; kc < nch; ++kc) {
        if (kc) __syncthreads();
        // stage Wt chunk: 128 rows x 256 B = 32 KB; 2048 x 16 B; 8 per thread
#pragma unroll
        for (int i = 0; i < 8; ++i) {
            int li = t + i * 256;
            int r = li >> 4;
            int cb = (li & 15) << 4;
            int4 v = *(const int4*)(Wt + (size_t)r * K + (kc << 7) + (cb >> 1));
            *(int4*)((char*)Ws + r * 256 + (cb ^ ((r & 7) << 4))) = v;
        }
        // A-frags straight from global (16 rows x 64 B, coalesced)
        short8v a[4];
        if (xrow) {
#pragma unroll
            for (int ks = 0; ks < 4; ++ks)
                a[ks] = *(const short8v*)(xrow + (kc << 7) + ks * 32 + kb * 8);
        } else {
#pragma unroll
            for (int ks = 0; ks < 4; ++ks) {
                const float* p = xrowf + (kc << 7) + ks * 32 + kb * 8;
                float4 f0 = *(const float4*)p;
                float4 f1 = *(const float4*)(p + 4);
                short8v av;
                av[0] = (short)f2bs(f0.x); av[1] = (short)f2bs(f0.y);
                av[2] = (short)f2bs(f0.z); av[3] = (short)f2bs(f0.w);
                av[4] = (short)f2bs(f1.x); av[5] = (short)f2bs(f1.y);
                av[6] = (short)f2bs(f1.z); av[7] = (short)f2bs(f1.w);
                a[ks] = av;
            }
        }
        __syncthreads();
#pragma unroll
        for (int ks = 0; ks < 4; ++ks) {
            int ofs = ks * 64 + kb * 16;
#pragma unroll
            for (int ct = 0; ct < 8; ++ct) {
                int c = ct * 16 + lr;
                short8v b = *(const short8v*)((const char*)Ws + c * 256 + (ofs ^ ((c & 7) << 4)));
                acc[ct] = __builtin_amdgcn_mfma_f32_16x16x32_bf16(a[ks], b, acc[ct], 0, 0, 0);
            }
        }
    }
    // epilogue: D[i][j]: j = ct*16+lr, i = kb*4+r
#pragma unroll
    for (int ct = 0; ct < 8; ++ct) {
        int col = ct * 16 + lr;
        float bv = bias ? bias[col] : 0.f;
#pragma unroll
        for (int r = 0; r < 4; ++r) {
            int grow = row0 + kb * 4 + r;
            if (grow < N) {
                float v = acc[ct][r] + bv;
                if (do_relu) v = fmaxf(v, 0.f);
                if (Yf) Yf[(size_t)grow * H + col] = v;
                else    Y[(size_t)grow * H + col] = f2bs(v);
            }
        }
    }
}

// ---------------- CSR build (XCD-partitioned scatter) ----------------
__global__ void zero2_kernel(int* __restrict__ a, int na, int* __restrict__ b, int nb) {
    int i = blockIdx.x * blockDim.x + threadIdx.x;
    int stride = gridDim.x * blockDim.x;
    for (int j = i; j < na; j += stride) a[j] = 0;
    for (int j = i; j < nb; j += stride) b[j] = 0;
}

// partition p = blockIdx%8 owns node ranges [p*RL,(p+1)*RL) / [p*RT,(p+1)*RT);
// its PBLK blocks cover all edges; only in-range nodes are counted -> XCD-local atomics.
__global__ void count_part(const int* __restrict__ es, const int* __restrict__ ed,
                           int* __restrict__ cl, int* __restrict__ ct, int E) {
    const int p = blockIdx.x & (NXCD - 1);
    const int pblk = blockIdx.x >> 3;
    const int RL = (N_LIG + NXCD - 1) / NXCD;
    const int RT = (N_TGT + NXCD - 1) / NXCD;
    const int lo_s = p * RL, hi_s = lo_s + RL;
    const int lo_d = p * RT, hi_d = lo_d + RT;
    for (int e = pblk * 256 + threadIdx.x; e < E; e += PBLK * 256) {
        int s = es[e], d = ed[e];
        if (s >= lo_s && s < hi_s) atomicAdd(&cl[s], 1);
        if (d >= lo_d && d < hi_d) atomicAdd(&ct[d], 1);
    }
}

// fill: ligand side stores (d, edge_id) int2 for the CSR-ordered edge pass;
// target side stores s only (gather index).
__global__ void fill_part(const int* __restrict__ es, const int* __restrict__ ed,
                          int* __restrict__ cur_l, int* __restrict__ cur_t,
                          int2* __restrict__ elist_l, int* __restrict__ nbr_t, int E) {
    const int p = blockIdx.x & (NXCD - 1);
    const int pblk = blockIdx.x >> 3;
    const int RL = (N_LIG + NXCD - 1) / NXCD;
    const int RT = (N_TGT + NXCD - 1) / NXCD;
    const int lo_s = p * RL, hi_s = lo_s + RL;
    const int lo_d = p * RT, hi_d = lo_d + RT;
    for (int e = pblk * 256 + threadIdx.x; e < E; e += PBLK * 256) {
        int s = es[e], d = ed[e];
        if (s >= lo_s && s < hi_s) elist_l[atomicAdd(&cur_l[s], 1)] = make_int2(d, e);
        if (d >= lo_d && d < hi_d) nbr_t[atomicAdd(&cur_t[d], 1)] = s;
    }
}

// merged hierarchical exclusive scan over the two count arrays
__global__ void scan_block2(const int* __restrict__ in_l, int* __restrict__ out_l,
                            int* __restrict__ bs_l, int nL, int nbL,
                            const int* __restrict__ in_t, int* __restrict__ out_t,
                            int* __restrict__ bs_t, int nT) {
    __shared__ int ts[256];
    const int* in; int* out; int* bsum; int n; int bi;
    if ((int)blockIdx.x < nbL) { in = in_l; out = out_l; bsum = bs_l; n = nL; bi = blockIdx.x; }
    else { in = in_t; out = out_t; bsum = bs_t; n = nT; bi = blockIdx.x - nbL; }
    int t = threadIdx.x;
    int base = bi * 1024 + t * 4;
    int v[4];
    int s = 0;
#pragma unroll
    for (int i = 0; i < 4; i++) {
        v[i] = (base + i < n) ? in[base + i] : 0;
        s += v[i];
    }
    ts[t] = s;
    __syncthreads();
    for (int ofs = 1; ofs < 256; ofs <<= 1) {
        int x = (t >= ofs) ? ts[t - ofs] : 0;
        __syncthreads();
        ts[t] += x;
        __syncthreads();
    }
    int run = (t == 0) ? 0 : ts[t - 1];
    if (t == 255) bsum[bi] = ts[255];
#pragma unroll
    for (int i = 0; i < 4; i++) {
        if (base + i < n) out[base + i] = run;
        run += v[i];
    }
}

__global__ void scan_top2(int* __restrict__ bs_l, int nbL, int* __restrict__ bs_t, int nbT) {
    __shared__ int ts[256];
    int* bsum = (blockIdx.x == 0) ? bs_l : bs_t;
    int nb = (blockIdx.x == 0) ? nbL : nbT;
    int t = threadIdx.x;
    ts[t] = (t < nb) ? bsum[t] : 0;
    __syncthreads();
    for (int ofs = 1; ofs < 256; ofs <<= 1) {
        int x = (t >= ofs) ? ts[t - ofs] : 0;
        __syncthreads();
        ts[t] += x;
        __syncthreads();
    }
    int excl = (t == 0) ? 0 : ts[t - 1];
    if (t < nb) bsum[t] = excl;
}

// adds block offsets, writes rowptr AND cursor copies, sets end sentinels
__global__ void add_off2(int* __restrict__ rp_l, const int* __restrict__ bs_l, int* __restrict__ cur_l,
                         int* __restrict__ rp_t, const int* __restrict__ bs_t, int* __restrict__ cur_t) {
    int i = blockIdx.x * blockDim.x + threadIdx.x;
    if (i < N_LIG) {
        int v = rp_l[i] + bs_l[i >> 10];
        rp_l[i] = v;
        cur_l[i] = v;
        if (i == 0) rp_l[N_LIG] = NEDGE;
    } else if (i < N_LIG + N_TGT) {
        int j = i - N_LIG;
        int v = rp_t[j] + bs_t[j >> 10];
        rp_t[j] = v;
        cur_t[j] = v;
        if (j == 0) rp_t[N_TGT] = NEDGE;
    }
}

// ---------------- gather-mean (bf16 in/out, fp32 accum): one wave per node ----------------
// nbr stride: 1 for plain int lists, 2 for int2 lists (index in .x)
__launch_bounds__(256)
__global__ void gather_mean_bf16(const unsigned short* __restrict__ feat,
                                 const int* __restrict__ rowptr, const int* __restrict__ nbr,
                                 int stride, unsigned short* __restrict__ out, int N) {
    int wid = (blockIdx.x * blockDim.x + threadIdx.x) >> 6;
    if (wid >= N) return;
    int lane = threadIdx.x & 63;
    int beg = rowptr[wid], end = rowptr[wid + 1];
    const unsigned int* f = (const unsigned int*)feat;  // 2 bf16 per uint
    float ax = 0.f, ay = 0.f;
    int j = beg;
    for (; j + 4 <= end; j += 4) {
        unsigned int v0 = f[(size_t)nbr[(j + 0) * stride] * 64 + lane];
        unsigned int v1 = f[(size_t)nbr[(j + 1) * stride] * 64 + lane];
        unsigned int v2 = f[(size_t)nbr[(j + 2) * stride] * 64 + lane];
        unsigned int v3 = f[(size_t)nbr[(j + 3) * stride] * 64 + lane];
        ax += bs2f(v0 & 0xffff) + bs2f(v1 & 0xffff) + bs2f(v2 & 0xffff) + bs2f(v3 & 0xffff);
        ay += bs2f(v0 >> 16) + bs2f(v1 >> 16) + bs2f(v2 >> 16) + bs2f(v3 >> 16);
    }
    for (; j < end; ++j) {
        unsigned int v = f[(size_t)nbr[j * stride] * 64 + lane];
        ax += bs2f(v & 0xffff);
        ay += bs2f(v >> 16);
    }
    float inv = 1.f / (float)max(end - beg, 1);
    unsigned int o = (unsigned int)f2bs(ax * inv) | ((unsigned int)f2bs(ay * inv) << 16);
    ((unsigned int*)out)[(size_t)wid * 64 + lane] = o;
}

// ---------------- edge MLP, ligand-major CSR order ----------------
// one wave per ligand node; A[s] (fp32) read once; B (bf16, 5 MB ~L2-resident) gathered.
// 4 groups x 16 lanes, one edge per group per iteration.
__launch_bounds__(256)
__global__ void edge_mlp_csr(const float* __restrict__ A, const unsigned short* __restrict__ B16,
                             const int* __restrict__ rowptr, const int2* __restrict__ elist,
                             const float* __restrict__ Wp2, const float* __restrict__ bp2,
                             float* __restrict__ out, int N) {
    int w = (blockIdx.x * blockDim.x + threadIdx.x) >> 6;
    if (w >= N) return;
    int lane = threadIdx.x & 63;
    int g = lane >> 4, l16 = lane & 15;
    int beg = rowptr[w], end = rowptr[w + 1];
    if (beg == end) return;
    float4 a0 = *(const float4*)&A[(size_t)w * H + l16 * 8];
    float4 a1 = *(const float4*)&A[(size_t)w * H + l16 * 8 + 4];
    float4 w0 = *(const float4*)&Wp2[l16 * 8];
    float4 w1 = *(const float4*)&Wp2[l16 * 8 + 4];
    float bp = bp2[0];
    for (int p = beg + g; p < end; p += 4) {
        int2 de = elist[p];
        uint4 ub = *(const uint4*)&B16[(size_t)de.x * H + l16 * 8];
        float acc =
            fmaxf(a0.x + bs2f(ub.x & 0xffff), 0.f) * w0.x +
            fmaxf(a0.y + bs2f(ub.x >> 16), 0.f) * w0.y +
            fmaxf(a0.z + bs2f(ub.y & 0xffff), 0.f) * w0.z +
            fmaxf(a0.w + bs2f(ub.y >> 16), 0.f) * w0.w +
            fmaxf(a1.x + bs2f(ub.z & 0xffff), 0.f) * w1.x +
            fmaxf(a1.y + bs2f(ub.z >> 16), 0.f) * w1.y +
            fmaxf(a1.z + bs2f(ub.w & 0xffff), 0.f) * w1.z +
            fmaxf(a1.w + bs2f(ub.w >> 16), 0.f) * w1.w;
        acc += __shfl_xor(acc, 8);
        acc += __shfl_xor(acc, 4);
        acc += __shfl_xor(acc, 2);
        acc += __shfl_xor(acc, 1);
        if (l16 == 0) out[de.y] = acc + bp;
    }
}

extern "C" void kernel_launch(void* const* d_in, const int* in_sizes, int n_in,
                              void* d_out, int out_size, void* d_ws, size_t ws_size,
                              hipStream_t stream) {
    const float* x_lig = (const float*)d_in[0];
    const float* x_tgt = (const float*)d_in[1];
    const int* es = (const int*)d_in[2];
    const int* ed = (const int*)d_in[3];
    const float* W_lig = (const float*)d_in[4];
    const float* b_lig = (const float*)d_in[5];
    const float* W_tgt = (const float*)d_in[6];
    const float* b_tgt = (const float*)d_in[7];
    const float* W1f = (const float*)d_in[8];
    const float* b1f = (const float*)d_in[9];
    const float* W1r = (const float*)d_in[10];
    const float* b1r = (const float*)d_in[11];
    const float* W2f = (const float*)d_in[12];
    const float* b2f = (const float*)d_in[13];
    const float* W2r = (const float*)d_in[14];
    const float* b2r = (const float*)d_in[15];
    const float* Wp1 = (const float*)d_in[16];
    const float* bp1 = (const float*)d_in[17];
    const float* Wp2 = (const float*)d_in[18];
    const float* bp2 = (const float*)d_in[19];
    float* out = (float*)d_out;

    char* base = (char*)d_ws;
    size_t off = 0;
    auto alloc = [&](size_t bytes) { char* p = base + off; off = (off + bytes + 255) & ~(size_t)255; return p; };
    unsigned short* L0 = (unsigned short*)alloc((size_t)N_LIG * H * 2);
    unsigned short* L1 = (unsigned short*)alloc((size_t)N_LIG * H * 2);
    unsigned short* T0 = (unsigned short*)alloc((size_t)N_TGT * H * 2);
    unsigned short* T1 = (unsigned short*)alloc((size_t)N_TGT * H * 2);  // agg_t / B16
    float* Af = (float*)alloc((size_t)N_LIG * H * 4);                    // 51.2 MB
    unsigned short* Wt_tgt = (unsigned short*)alloc((size_t)128 * 1280 * 2);
    unsigned short* Wt1f = (unsigned short*)alloc(128 * 128 * 2);
    unsigned short* Wt1r = (unsigned short*)alloc(128 * 128 * 2);
    unsigned short* Wt2f = (unsigned short*)alloc(128 * 128 * 2);
    unsigned short* Wt2r = (unsigned short*)alloc(128 * 128 * 2);
    unsigned short* WtA = (unsigned short*)alloc(128 * 128 * 2);
    unsigned short* WtB = (unsigned short*)alloc(128 * 128 * 2);
    int* cnt_l = (int*)alloc(N_LIG * 4);
    int* cnt_t = (int*)alloc(N_TGT * 4);
    int* rowptr_l = (int*)alloc((N_LIG + 4) * 4);
    int* rowptr_t = (int*)alloc((N_TGT + 4) * 4);
    int* cur_l = (int*)alloc(N_LIG * 4);
    int* cur_t = (int*)alloc(N_TGT * 4);
    int* bsum_l = (int*)alloc(256 * 4);
    int* bsum_t = (int*)alloc(256 * 4);
    int2* elist_l = (int2*)alloc((size_t)NEDGE * 8);  // (d, edge_id), ligand-CSR order
    int* nbr_t = (int*)alloc((size_t)NEDGE * 4);

    const int ligBlocks = (N_LIG + 63) / 64;
    const int tgtBlocks = (N_TGT + 63) / 64;
    const int nbL = (N_LIG + 1023) / 1024;   // 98
    const int nbT = (N_TGT + 1023) / 1024;   // 20

    // 0. weight prep (transpose + bf16)
    transpose_w<<<(1280 * 128 + 255) / 256, 256, 0, stream>>>(W_tgt, Wt_tgt, 1280);
    P6 p6;
    p6.w[0] = W1f; p6.o[0] = Wt1f;
    p6.w[1] = W1r; p6.o[1] = Wt1r;
    p6.w[2] = W2f; p6.o[2] = Wt2f;
    p6.w[3] = W2r; p6.o[3] = Wt2r;
    p6.w[4] = Wp1;           p6.o[4] = WtA;   // top half rows 0..127
    p6.w[5] = Wp1 + 128 * H; p6.o[5] = WtB;   // bottom half
    transpose6<<<6 * 64, 256, 0, stream>>>(p6);

    // 1. node embeddings (x_tgt converted to bf16 in-register inside the GEMM)
    lin4_bf16<<<(N_LIG * 16 + 255) / 256, 256, 0, stream>>>(x_lig, W_lig, b_lig, L0, N_LIG);
    gemm_bf16<<<tgtBlocks, 256, 0, stream>>>(nullptr, x_tgt, Wt_tgt, b_tgt, T0, nullptr, N_TGT, 1280, 0);

    // 2. CSR build, XCD-partitioned
    zero2_kernel<<<120, 256, 0, stream>>>(cnt_l, N_LIG, cnt_t, N_TGT);
    count_part<<<NXCD * PBLK, 256, 0, stream>>>(es, ed, cnt_l, cnt_t, NEDGE);
    scan_block2<<<nbL + nbT, 256, 0, stream>>>(cnt_l, rowptr_l, bsum_l, N_LIG, nbL,
                                               cnt_t, rowptr_t, bsum_t, N_TGT);
    scan_top2<<<2, 256, 0, stream>>>(bsum_l, nbL, bsum_t, nbT);
    add_off2<<<(N_LIG + N_TGT + 255) / 256, 256, 0, stream>>>(rowptr_l, bsum_l, cur_l,
                                                              rowptr_t, bsum_t, cur_t);
    fill_part<<<NXCD * PBLK, 256, 0, stream>>>(es, ed, cur_l, cur_t, elist_l, nbr_t, NEDGE);

    // 3. two conv layers (gather-mean + MFMA GEMM)
    const unsigned short* Wtf[2] = {Wt1f, Wt2f};
    const float* bfp[2] = {b1f, b2f};
    const unsigned short* Wtr[2] = {Wt1r, Wt2r};
    const float* brp[2] = {b1r, b2r};
    for (int layer = 0; layer < 2; ++layer) {
        gather_mean_bf16<<<(N_TGT * 64 + 255) / 256, 256, 0, stream>>>(L0, rowptr_t, nbr_t, 1, T1, N_TGT);
        gather_mean_bf16<<<(N_LIG * 64 + 255) / 256, 256, 0, stream>>>(T0, rowptr_l, (const int*)elist_l, 2, L1, N_LIG);
        gemm_bf16<<<tgtBlocks, 256, 0, stream>>>(T1, nullptr, Wtf[layer], bfp[layer], T0, nullptr, N_TGT, 128, 1);
        gemm_bf16<<<ligBlocks, 256, 0, stream>>>(L1, nullptr, Wtr[layer], brp[layer], L0, nullptr, N_LIG, 128, 1);
    }

    // 4. edge-MLP factorization: A (fp32) = h_lig @ Wp1_top; B (bf16) = h_tgt @ Wp1_bot + bp1
    gemm_bf16<<<ligBlocks, 256, 0, stream>>>(L0, nullptr, WtA, nullptr, nullptr, Af, N_LIG, 128, 0);
    gemm_bf16<<<tgtBlocks, 256, 0, stream>>>(T0, nullptr, WtB, bp1, T1, nullptr, N_TGT, 128, 0);

    // 5. per-edge, ligand-major: pred = relu(A[s]+B[d]) . Wp2 + bp2
    edge_mlp_csr<<<(N_LIG * 64 + 255) / 256, 256, 0, stream>>>(
        Af, T1, rowptr_l, elist_l, Wp2, bp2, out, N_LIG);
}

// Round 7
// 583.909 us; speedup vs baseline: 12.9454x; 1.0409x over previous
//
#include <hip/hip_runtime.h>
#include <hip/hip_bf16.h>

#define N_LIG 100000
#define N_TGT 20000
#define NEDGE 1000000
#define H 128
#define NXCD 8
#define RL 12500   // ligand ids per partition
#define RT 2500    // target ids per partition
#define CAP 131072 // per-bucket capacity (mean 125000, sigma ~331)

typedef __attribute__((ext_vector_type(8))) short short8v;
typedef __attribute__((ext_vector_type(4))) float f32x4;

// ---- bf16 helpers (manual RTN-even, bit ops only) ----
__device__ __forceinline__ unsigned short f2bs(float f) {
    unsigned int u = __float_as_uint(f);
    u += 0x7fff + ((u >> 16) & 1);
    return (unsigned short)(u >> 16);
}
__device__ __forceinline__ float bs2f(unsigned int s) {
    return __uint_as_float(s << 16);
}

// ---------------- weight transpose+convert: W[K][128] f32 -> Wt[128][K] bf16 ----------------
__global__ void transpose_w(const float* __restrict__ W, unsigned short* __restrict__ Wt, int K) {
    int idx = blockIdx.x * blockDim.x + threadIdx.x;
    if (idx >= K * 128) return;
    int k = idx >> 7, c = idx & 127;
    Wt[(size_t)c * K + k] = f2bs(W[idx]);
}

// six 128x128 transposes in one launch
struct P6 { const float* w[6]; unsigned short* o[6]; };
__global__ void transpose6(P6 p) {
    int idx = blockIdx.x * blockDim.x + threadIdx.x;  // 6*16384
    int which = idx >> 14;
    int rem = idx & 16383;
    int k = rem >> 7, c = rem & 127;
    p.o[which][(size_t)c * 128 + k] = f2bs(p.w[which][rem]);
}

// ---------------- ligand embed: K=4, bf16 out ----------------
__global__ void lin4_bf16(const float* __restrict__ X, const float* __restrict__ W,
                          const float* __restrict__ b, unsigned short* __restrict__ Y, int N) {
    int idx = blockIdx.x * blockDim.x + threadIdx.x;  // N*16, 8 cols each
    if (idx >= N * 16) return;
    int r = idx >> 4;
    int c = (idx & 15) * 8;
    float x0 = X[r * 4 + 0], x1 = X[r * 4 + 1], x2 = X[r * 4 + 2], x3 = X[r * 4 + 3];
    unsigned int o[4];
#pragma unroll
    for (int p = 0; p < 4; ++p) {
        float v0 = b[c + 2 * p] + x0 * W[c + 2 * p] + x1 * W[H + c + 2 * p] +
                   x2 * W[2 * H + c + 2 * p] + x3 * W[3 * H + c + 2 * p];
        float v1 = b[c + 2 * p + 1] + x0 * W[c + 2 * p + 1] + x1 * W[H + c + 2 * p + 1] +
                   x2 * W[2 * H + c + 2 * p + 1] + x3 * W[3 * H + c + 2 * p + 1];
        o[p] = (unsigned int)f2bs(v0) | ((unsigned int)f2bs(v1) << 16);
    }
    uint4 u = make_uint4(o[0], o[1], o[2], o[3]);
    *(uint4*)&Y[(size_t)r * H + c] = u;
}

// ---------------- MFMA GEMM: act(X[N][K] @ W + bias) -> Y (bf16) or Yf (fp32) ----------------
__launch_bounds__(256)
__global__ void gemm_bf16(const unsigned short* __restrict__ X,
                          const float* __restrict__ Xf32,
                          const unsigned short* __restrict__ Wt,
                          const float* __restrict__ bias,
                          unsigned short* __restrict__ Y,
                          float* __restrict__ Yf,
                          int N, int K, int do_relu) {
    __shared__ unsigned short Ws[128 * 128];  // 32 KB, rows of 256 B, XOR-swizzled
    const int t = threadIdx.x;
    const int wv = t >> 6;
    const int lane = t & 63;
    const int lr = lane & 15;
    const int kb = lane >> 4;
    const int row0 = blockIdx.x * 64 + wv * 16;

    f32x4 acc[8];
#pragma unroll
    for (int i = 0; i < 8; ++i) acc[i] = (f32x4){0.f, 0.f, 0.f, 0.f};

    int arow = row0 + lr;
    if (arow >= N) arow = N - 1;
    const unsigned short* xrow = X ? X + (size_t)arow * K : nullptr;
    const float* xrowf = Xf32 ? Xf32 + (size_t)arow * K : nullptr;

    const int nch = K >> 7;
    for (int kc = 0; kc < nch; ++kc) {
        if (kc) __syncthreads();
#pragma unroll
        for (int i = 0; i < 8; ++i) {
            int li = t + i * 256;
            int r = li >> 4;
            int cb = (li & 15) << 4;
            int4 v = *(const int4*)(Wt + (size_t)r * K + (kc << 7) + (cb >> 1));
            *(int4*)((char*)Ws + r * 256 + (cb ^ ((r & 7) << 4))) = v;
        }
        short8v a[4];
        if (xrow) {
#pragma unroll
            for (int ks = 0; ks < 4; ++ks)
                a[ks] = *(const short8v*)(xrow + (kc << 7) + ks * 32 + kb * 8);
        } else {
#pragma unroll
            for (int ks = 0; ks < 4; ++ks) {
                const float* p = xrowf + (kc << 7) + ks * 32 + kb * 8;
                float4 f0 = *(const float4*)p;
                float4 f1 = *(const float4*)(p + 4);
                short8v av;
                av[0] = (short)f2bs(f0.x); av[1] = (short)f2bs(f0.y);
                av[2] = (short)f2bs(f0.z); av[3] = (short)f2bs(f0.w);
                av[4] = (short)f2bs(f1.x); av[5] = (short)f2bs(f1.y);
                av[6] = (short)f2bs(f1.z); av[7] = (short)f2bs(f1.w);
                a[ks] = av;
            }
        }
        __syncthreads();
#pragma unroll
        for (int ks = 0; ks < 4; ++ks) {
            int ofs = ks * 64 + kb * 16;
#pragma unroll
            for (int ct = 0; ct < 8; ++ct) {
                int c = ct * 16 + lr;
                short8v b = *(const short8v*)((const char*)Ws + c * 256 + (ofs ^ ((c & 7) << 4)));
                acc[ct] = __builtin_amdgcn_mfma_f32_16x16x32_bf16(a[ks], b, acc[ct], 0, 0, 0);
            }
        }
    }
#pragma unroll
    for (int ct = 0; ct < 8; ++ct) {
        int col = ct * 16 + lr;
        float bv = bias ? bias[col] : 0.f;
#pragma unroll
        for (int r = 0; r < 4; ++r) {
            int grow = row0 + kb * 4 + r;
            if (grow < N) {
                float v = acc[ct][r] + bv;
                if (do_relu) v = fmaxf(v, 0.f);
                if (Yf) Yf[(size_t)grow * H + col] = v;
                else    Y[(size_t)grow * H + col] = f2bs(v);
            }
        }
    }
}

// ---------------- CSR build: phase 1 — bin edges into 8 XCD-local buckets ----------------
// lig entry: uint64 (e<<32) | (d<<17) | s ; tgt entry: uint32 (d<<17) | s
__global__ void zero3_kernel(int* __restrict__ a, int na, int* __restrict__ b, int nb,
                             int* __restrict__ c, int nc) {
    int i = blockIdx.x * blockDim.x + threadIdx.x;
    int stride = gridDim.x * blockDim.x;
    for (int j = i; j < na; j += stride) a[j] = 0;
    for (int j = i; j < nb; j += stride) b[j] = 0;
    for (int j = i; j < nc; j += stride) c[j] = 0;
}

__launch_bounds__(256)
__global__ void bin_edges(const int* __restrict__ es, const int* __restrict__ ed,
                          unsigned long long* __restrict__ bkt_l, unsigned int* __restrict__ bkt_t,
                          int* __restrict__ gcur, int E) {
    __shared__ int h[16];
    __shared__ int base[16];
    int t = threadIdx.x;
    if (t < 16) h[t] = 0;
    __syncthreads();
    int chunk = (E + gridDim.x - 1) / gridDim.x;
    int beg = blockIdx.x * chunk;
    int end = min(beg + chunk, E);
    for (int e = beg + t; e < end; e += 256) {
        int s = es[e], d = ed[e];
        atomicAdd(&h[s / RL], 1);
        atomicAdd(&h[8 + d / RT], 1);
    }
    __syncthreads();
    if (t < 16) {
        base[t] = atomicAdd(&gcur[t], h[t]);
        h[t] = 0;
    }
    __syncthreads();
    for (int e = beg + t; e < end; e += 256) {
        int s = es[e], d = ed[e];
        int bl = s / RL, bt = d / RT;
        unsigned int low = ((unsigned int)d << 17) | (unsigned int)s;
        int il = base[bl] + atomicAdd(&h[bl], 1);
        il = min(il, CAP - 1);
        bkt_l[(size_t)bl * CAP + il] = ((unsigned long long)(unsigned int)e << 32) | low;
        int it = base[8 + bt] + atomicAdd(&h[8 + bt], 1);
        it = min(it, CAP - 1);
        bkt_t[(size_t)bt * CAP + it] = low;
    }
}

// ---------------- phase 2a: count per node (XCD-local) ----------------
__launch_bounds__(256)
__global__ void count_bucket(const unsigned long long* __restrict__ bkt_l,
                             const unsigned int* __restrict__ bkt_t,
                             const int* __restrict__ gcur,
                             int* __restrict__ cnt_l, int* __restrict__ cnt_t) {
    const int p = blockIdx.x & (NXCD - 1);
    const int pblk = blockIdx.x >> 3;
    const int nblk = gridDim.x >> 3;
    int nL = min(gcur[p], CAP), nT = min(gcur[8 + p], CAP);
    const unsigned long long* bl = bkt_l + (size_t)p * CAP;
    const unsigned int* bt = bkt_t + (size_t)p * CAP;
    for (int i = pblk * 256 + threadIdx.x; i < nL; i += nblk * 256)
        atomicAdd(&cnt_l[(unsigned int)bl[i] & 0x1FFFF], 1);
    for (int i = pblk * 256 + threadIdx.x; i < nT; i += nblk * 256)
        atomicAdd(&cnt_t[bt[i] >> 17], 1);
}

// ---------------- phase 2b: fill CSR lists (XCD-local) ----------------
__launch_bounds__(256)
__global__ void fill_bucket(const unsigned long long* __restrict__ bkt_l,
                            const unsigned int* __restrict__ bkt_t,
                            const int* __restrict__ gcur,
                            int* __restrict__ cur_l, int* __restrict__ cur_t,
                            int2* __restrict__ elist_l, int* __restrict__ nbr_t) {
    const int p = blockIdx.x & (NXCD - 1);
    const int pblk = blockIdx.x >> 3;
    const int nblk = gridDim.x >> 3;
    int nL = min(gcur[p], CAP), nT = min(gcur[8 + p], CAP);
    const unsigned long long* bl = bkt_l + (size_t)p * CAP;
    const unsigned int* bt = bkt_t + (size_t)p * CAP;
    for (int i = pblk * 256 + threadIdx.x; i < nL; i += nblk * 256) {
        unsigned long long v = bl[i];
        unsigned int low = (unsigned int)v;
        int s = low & 0x1FFFF;
        int d = (low >> 17) & 0x7FFF;
        int e = (int)(v >> 32);
        elist_l[atomicAdd(&cur_l[s], 1)] = make_int2(d, e);
    }
    for (int i = pblk * 256 + threadIdx.x; i < nT; i += nblk * 256) {
        unsigned int v = bt[i];
        nbr_t[atomicAdd(&cur_t[v >> 17], 1)] = v & 0x1FFFF;
    }
}

// merged hierarchical exclusive scan over the two count arrays
__global__ void scan_block2(const int* __restrict__ in_l, int* __restrict__ out_l,
                            int* __restrict__ bs_l, int nL, int nbL,
                            const int* __restrict__ in_t, int* __restrict__ out_t,
                            int* __restrict__ bs_t, int nT) {
    __shared__ int ts[256];
    const int* in; int* out; int* bsum; int n; int bi;
    if ((int)blockIdx.x < nbL) { in = in_l; out = out_l; bsum = bs_l; n = nL; bi = blockIdx.x; }
    else { in = in_t; out = out_t; bsum = bs_t; n = nT; bi = blockIdx.x - nbL; }
    int t = threadIdx.x;
    int base = bi * 1024 + t * 4;
    int v[4];
    int s = 0;
#pragma unroll
    for (int i = 0; i < 4; i++) {
        v[i] = (base + i < n) ? in[base + i] : 0;
        s += v[i];
    }
    ts[t] = s;
    __syncthreads();
    for (int ofs = 1; ofs < 256; ofs <<= 1) {
        int x = (t >= ofs) ? ts[t - ofs] : 0;
        __syncthreads();
        ts[t] += x;
        __syncthreads();
    }
    int run = (t == 0) ? 0 : ts[t - 1];
    if (t == 255) bsum[bi] = ts[255];
#pragma unroll
    for (int i = 0; i < 4; i++) {
        if (base + i < n) out[base + i] = run;
        run += v[i];
    }
}

__global__ void scan_top2(int* __restrict__ bs_l, int nbL, int* __restrict__ bs_t, int nbT) {
    __shared__ int ts[256];
    int* bsum = (blockIdx.x == 0) ? bs_l : bs_t;
    int nb = (blockIdx.x == 0) ? nbL : nbT;
    int t = threadIdx.x;
    ts[t] = (t < nb) ? bsum[t] : 0;
    __syncthreads();
    for (int ofs = 1; ofs < 256; ofs <<= 1) {
        int x = (t >= ofs) ? ts[t - ofs] : 0;
        __syncthreads();
        ts[t] += x;
        __syncthreads();
    }
    int excl = (t == 0) ? 0 : ts[t - 1];
    if (t < nb) bsum[t] = excl;
}

__global__ void add_off2(int* __restrict__ rp_l, const int* __restrict__ bs_l, int* __restrict__ cur_l,
                         int* __restrict__ rp_t, const int* __restrict__ bs_t, int* __restrict__ cur_t) {
    int i = blockIdx.x * blockDim.x + threadIdx.x;
    if (i < N_LIG) {
        int v = rp_l[i] + bs_l[i >> 10];
        rp_l[i] = v;
        cur_l[i] = v;
        if (i == 0) rp_l[N_LIG] = NEDGE;
    } else if (i < N_LIG + N_TGT) {
        int j = i - N_LIG;
        int v = rp_t[j] + bs_t[j >> 10];
        rp_t[j] = v;
        cur_t[j] = v;
        if (j == 0) rp_t[N_TGT] = NEDGE;
    }
}

// ---------------- gather-mean (bf16 in/out, fp32 accum): one wave per node ----------------
__launch_bounds__(256)
__global__ void gather_mean_bf16(const unsigned short* __restrict__ feat,
                                 const int* __restrict__ rowptr, const int* __restrict__ nbr,
                                 int stride, unsigned short* __restrict__ out, int N) {
    int wid = (blockIdx.x * blockDim.x + threadIdx.x) >> 6;
    if (wid >= N) return;
    int lane = threadIdx.x & 63;
    int beg = rowptr[wid], end = rowptr[wid + 1];
    const unsigned int* f = (const unsigned int*)feat;  // 2 bf16 per uint
    float ax = 0.f, ay = 0.f;
    int j = beg;
    for (; j + 8 <= end; j += 8) {
        unsigned int v[8];
#pragma unroll
        for (int q = 0; q < 8; ++q) v[q] = f[(size_t)nbr[(j + q) * stride] * 64 + lane];
#pragma unroll
        for (int q = 0; q < 8; ++q) { ax += bs2f(v[q] & 0xffff); ay += bs2f(v[q] >> 16); }
    }
    for (; j + 2 <= end; j += 2) {
        unsigned int v0 = f[(size_t)nbr[(j + 0) * stride] * 64 + lane];
        unsigned int v1 = f[(size_t)nbr[(j + 1) * stride] * 64 + lane];
        ax += bs2f(v0 & 0xffff) + bs2f(v1 & 0xffff);
        ay += bs2f(v0 >> 16) + bs2f(v1 >> 16);
    }
    for (; j < end; ++j) {
        unsigned int v = f[(size_t)nbr[j * stride] * 64 + lane];
        ax += bs2f(v & 0xffff);
        ay += bs2f(v >> 16);
    }
    float inv = 1.f / (float)max(end - beg, 1);
    unsigned int o = (unsigned int)f2bs(ax * inv) | ((unsigned int)f2bs(ay * inv) << 16);
    ((unsigned int*)out)[(size_t)wid * 64 + lane] = o;
}

// ---------------- edge MLP, ligand-major CSR order ----------------
__launch_bounds__(256)
__global__ void edge_mlp_csr(const float* __restrict__ A, const unsigned short* __restrict__ B16,
                             const int* __restrict__ rowptr, const int2* __restrict__ elist,
                             const float* __restrict__ Wp2, const float* __restrict__ bp2,
                             float* __restrict__ out, int N) {
    int w = (blockIdx.x * blockDim.x + threadIdx.x) >> 6;
    if (w >= N) return;
    int lane = threadIdx.x & 63;
    int g = lane >> 4, l16 = lane & 15;
    int beg = rowptr[w], end = rowptr[w + 1];
    if (beg == end) return;
    float4 a0 = *(const float4*)&A[(size_t)w * H + l16 * 8];
    float4 a1 = *(const float4*)&A[(size_t)w * H + l16 * 8 + 4];
    float4 w0 = *(const float4*)&Wp2[l16 * 8];
    float4 w1 = *(const float4*)&Wp2[l16 * 8 + 4];
    float bp = bp2[0];
    for (int p = beg + g; p < end; p += 4) {
        int2 de = elist[p];
        uint4 ub = *(const uint4*)&B16[(size_t)de.x * H + l16 * 8];
        float acc =
            fmaxf(a0.x + bs2f(ub.x & 0xffff), 0.f) * w0.x +
            fmaxf(a0.y + bs2f(ub.x >> 16), 0.f) * w0.y +
            fmaxf(a0.z + bs2f(ub.y & 0xffff), 0.f) * w0.z +
            fmaxf(a0.w + bs2f(ub.y >> 16), 0.f) * w0.w +
            fmaxf(a1.x + bs2f(ub.z & 0xffff), 0.f) * w1.x +
            fmaxf(a1.y + bs2f(ub.z >> 16), 0.f) * w1.y +
            fmaxf(a1.z + bs2f(ub.w & 0xffff), 0.f) * w1.z +
            fmaxf(a1.w + bs2f(ub.w >> 16), 0.f) * w1.w;
        acc += __shfl_xor(acc, 8);
        acc += __shfl_xor(acc, 4);
        acc += __shfl_xor(acc, 2);
        acc += __shfl_xor(acc, 1);
        if (l16 == 0) out[de.y] = acc + bp;
    }
}

extern "C" void kernel_launch(void* const* d_in, const int* in_sizes, int n_in,
                              void* d_out, int out_size, void* d_ws, size_t ws_size,
                              hipStream_t stream) {
    const float* x_lig = (const float*)d_in[0];
    const float* x_tgt = (const float*)d_in[1];
    const int* es = (const int*)d_in[2];
    const int* ed = (const int*)d_in[3];
    const float* W_lig = (const float*)d_in[4];
    const float* b_lig = (const float*)d_in[5];
    const float* W_tgt = (const float*)d_in[6];
    const float* b_tgt = (const float*)d_in[7];
    const float* W1f = (const float*)d_in[8];
    const float* b1f = (const float*)d_in[9];
    const float* W1r = (const float*)d_in[10];
    const float* b1r = (const float*)d_in[11];
    const float* W2f = (const float*)d_in[12];
    const float* b2f = (const float*)d_in[13];
    const float* W2r = (const float*)d_in[14];
    const float* b2r = (const float*)d_in[15];
    const float* Wp1 = (const float*)d_in[16];
    const float* bp1 = (const float*)d_in[17];
    const float* Wp2 = (const float*)d_in[18];
    const float* bp2 = (const float*)d_in[19];
    float* out = (float*)d_out;

    char* base = (char*)d_ws;
    size_t off = 0;
    auto alloc = [&](size_t bytes) { char* p = base + off; off = (off + bytes + 255) & ~(size_t)255; return p; };
    unsigned short* L0 = (unsigned short*)alloc((size_t)N_LIG * H * 2);
    unsigned short* L1 = (unsigned short*)alloc((size_t)N_LIG * H * 2);
    unsigned short* T0 = (unsigned short*)alloc((size_t)N_TGT * H * 2);
    unsigned short* T1 = (unsigned short*)alloc((size_t)N_TGT * H * 2);  // agg_t / B16
    float* Af = (float*)alloc((size_t)N_LIG * H * 4);                    // 51.2 MB
    unsigned short* Wt_tgt = (unsigned short*)alloc((size_t)128 * 1280 * 2);
    unsigned short* Wt1f = (unsigned short*)alloc(128 * 128 * 2);
    unsigned short* Wt1r = (unsigned short*)alloc(128 * 128 * 2);
    unsigned short* Wt2f = (unsigned short*)alloc(128 * 128 * 2);
    unsigned short* Wt2r = (unsigned short*)alloc(128 * 128 * 2);
    unsigned short* WtA = (unsigned short*)alloc(128 * 128 * 2);
    unsigned short* WtB = (unsigned short*)alloc(128 * 128 * 2);
    int* cnt_l = (int*)alloc(N_LIG * 4);
    int* cnt_t = (int*)alloc(N_TGT * 4);
    int* rowptr_l = (int*)alloc((N_LIG + 4) * 4);
    int* rowptr_t = (int*)alloc((N_TGT + 4) * 4);
    int* cur_l = (int*)alloc(N_LIG * 4);
    int* cur_t = (int*)alloc(N_TGT * 4);
    int* bsum_l = (int*)alloc(256 * 4);
    int* bsum_t = (int*)alloc(256 * 4);
    int* gcur = (int*)alloc(16 * 4);
    int2* elist_l = (int2*)alloc((size_t)NEDGE * 8);  // (d, edge_id), ligand-CSR order
    int* nbr_t = (int*)alloc((size_t)NEDGE * 4);
    unsigned long long* bkt_l = (unsigned long long*)alloc((size_t)NXCD * CAP * 8);  // 8.4 MB
    unsigned int* bkt_t = (unsigned int*)alloc((size_t)NXCD * CAP * 4);              // 4.2 MB

    const int ligBlocks = (N_LIG + 63) / 64;
    const int tgtBlocks = (N_TGT + 63) / 64;
    const int nbL = (N_LIG + 1023) / 1024;   // 98
    const int nbT = (N_TGT + 1023) / 1024;   // 20

    // 0. weight prep (transpose + bf16)
    transpose_w<<<(1280 * 128 + 255) / 256, 256, 0, stream>>>(W_tgt, Wt_tgt, 1280);
    P6 p6;
    p6.w[0] = W1f; p6.o[0] = Wt1f;
    p6.w[1] = W1r; p6.o[1] = Wt1r;
    p6.w[2] = W2f; p6.o[2] = Wt2f;
    p6.w[3] = W2r; p6.o[3] = Wt2r;
    p6.w[4] = Wp1;           p6.o[4] = WtA;
    p6.w[5] = Wp1 + 128 * H; p6.o[5] = WtB;
    transpose6<<<6 * 64, 256, 0, stream>>>(p6);

    // 1. node embeddings (x_tgt converted to bf16 in-register inside the GEMM)
    lin4_bf16<<<(N_LIG * 16 + 255) / 256, 256, 0, stream>>>(x_lig, W_lig, b_lig, L0, N_LIG);
    gemm_bf16<<<tgtBlocks, 256, 0, stream>>>(nullptr, x_tgt, Wt_tgt, b_tgt, T0, nullptr, N_TGT, 1280, 0);

    // 2. CSR build: bin -> count -> scan -> fill
    zero3_kernel<<<120, 256, 0, stream>>>(cnt_l, N_LIG, cnt_t, N_TGT, gcur, 16);
    bin_edges<<<512, 256, 0, stream>>>(es, ed, bkt_l, bkt_t, gcur, NEDGE);
    count_bucket<<<NXCD * 64, 256, 0, stream>>>(bkt_l, bkt_t, gcur, cnt_l, cnt_t);
    scan_block2<<<nbL + nbT, 256, 0, stream>>>(cnt_l, rowptr_l, bsum_l, N_LIG, nbL,
                                               cnt_t, rowptr_t, bsum_t, N_TGT);
    scan_top2<<<2, 256, 0, stream>>>(bsum_l, nbL, bsum_t, nbT);
    add_off2<<<(N_LIG + N_TGT + 255) / 256, 256, 0, stream>>>(rowptr_l, bsum_l, cur_l,
                                                              rowptr_t, bsum_t, cur_t);
    fill_bucket<<<NXCD * 64, 256, 0, stream>>>(bkt_l, bkt_t, gcur, cur_l, cur_t, elist_l, nbr_t);

    // 3. two conv layers (gather-mean + MFMA GEMM)
    const unsigned short* Wtf[2] = {Wt1f, Wt2f};
    const float* bfp[2] = {b1f, b2f};
    const unsigned short* Wtr[2] = {Wt1r, Wt2r};
    const float* brp[2] = {b1r, b2r};
    for (int layer = 0; layer < 2; ++layer) {
        gather_mean_bf16<<<(N_TGT * 64 + 255) / 256, 256, 0, stream>>>(L0, rowptr_t, nbr_t, 1, T1, N_TGT);
        gather_mean_bf16<<<(N_LIG * 64 + 255) / 256, 256, 0, stream>>>(T0, rowptr_l, (const int*)elist_l, 2, L1, N_LIG);
        gemm_bf16<<<tgtBlocks, 256, 0, stream>>>(T1, nullptr, Wtf[layer], bfp[layer], T0, nullptr, N_TGT, 128, 1);
        gemm_bf16<<<ligBlocks, 256, 0, stream>>>(L1, nullptr, Wtr[layer], brp[layer], L0, nullptr, N_LIG, 128, 1);
    }

    // 4. edge-MLP factorization: A (fp32) = h_lig @ Wp1_top; B (bf16) = h_tgt @ Wp1_bot + bp1
    gemm_bf16<<<ligBlocks, 256, 0, stream>>>(L0, nullptr, WtA, nullptr, nullptr, Af, N_LIG, 128, 0);
    gemm_bf16<<<tgtBlocks, 256, 0, stream>>>(T0, nullptr, WtB, bp1, T1, nullptr, N_TGT, 128, 0);

    // 5. per-edge, ligand-major: pred = relu(A[s]+B[d]) . Wp2 + bp2
    edge_mlp_csr<<<(N_LIG * 64 + 255) / 256, 256, 0, stream>>>(
        Af, T1, rowptr_l, elist_l, Wp2, bp2, out, N_LIG);
}

// Round 8
// 494.783 us; speedup vs baseline: 15.2773x; 1.1801x over previous
//
#include <hip/hip_runtime.h>
#include <hip/hip_bf16.h>

#define N_LIG 100000
#define N_TGT 20000
#define NEDGE 1000000
#define H 128
#define NXCD 8
#define RL 12500   // ligand ids per partition (8*12500 = 100000)
#define RT 2500    // target ids per partition (8*2500 = 20000)
#define CAP 131072 // per-bucket capacity (mean 125000, sigma ~331)
#define NSLICE 32  // sub-slices per bucket for count/fill

typedef __attribute__((ext_vector_type(8))) short short8v;
typedef __attribute__((ext_vector_type(4))) float f32x4;

// ---- bf16 helpers (manual RTN-even, bit ops only) ----
__device__ __forceinline__ unsigned short f2bs(float f) {
    unsigned int u = __float_as_uint(f);
    u += 0x7fff + ((u >> 16) & 1);
    return (unsigned short)(u >> 16);
}
__device__ __forceinline__ float bs2f(unsigned int s) {
    return __uint_as_float(s << 16);
}

// ---------------- weight transpose+convert: W[K][128] f32 -> Wt[128][K] bf16 ----------------
__global__ void transpose_w(const float* __restrict__ W, unsigned short* __restrict__ Wt, int K) {
    int idx = blockIdx.x * blockDim.x + threadIdx.x;
    if (idx >= K * 128) return;
    int k = idx >> 7, c = idx & 127;
    Wt[(size_t)c * K + k] = f2bs(W[idx]);
}

// six 128x128 transposes in one launch
struct P6 { const float* w[6]; unsigned short* o[6]; };
__global__ void transpose6(P6 p) {
    int idx = blockIdx.x * blockDim.x + threadIdx.x;  // 6*16384
    int which = idx >> 14;
    int rem = idx & 16383;
    int k = rem >> 7, c = rem & 127;
    p.o[which][(size_t)c * 128 + k] = f2bs(p.w[which][rem]);
}

// ---------------- ligand embed: K=4, bf16 out ----------------
__global__ void lin4_bf16(const float* __restrict__ X, const float* __restrict__ W,
                          const float* __restrict__ b, unsigned short* __restrict__ Y, int N) {
    int idx = blockIdx.x * blockDim.x + threadIdx.x;  // N*16, 8 cols each
    if (idx >= N * 16) return;
    int r = idx >> 4;
    int c = (idx & 15) * 8;
    float x0 = X[r * 4 + 0], x1 = X[r * 4 + 1], x2 = X[r * 4 + 2], x3 = X[r * 4 + 3];
    unsigned int o[4];
#pragma unroll
    for (int p = 0; p < 4; ++p) {
        float v0 = b[c + 2 * p] + x0 * W[c + 2 * p] + x1 * W[H + c + 2 * p] +
                   x2 * W[2 * H + c + 2 * p] + x3 * W[3 * H + c + 2 * p];
        float v1 = b[c + 2 * p + 1] + x0 * W[c + 2 * p + 1] + x1 * W[H + c + 2 * p + 1] +
                   x2 * W[2 * H + c + 2 * p + 1] + x3 * W[3 * H + c + 2 * p + 1];
        o[p] = (unsigned int)f2bs(v0) | ((unsigned int)f2bs(v1) << 16);
    }
    uint4 u = make_uint4(o[0], o[1], o[2], o[3]);
    *(uint4*)&Y[(size_t)r * H + c] = u;
}

// ---------------- MFMA GEMM: act(X[N][K] @ W + bias) -> Y (bf16) or Yf (fp32) ----------------
__launch_bounds__(256)
__global__ void gemm_bf16(const unsigned short* __restrict__ X,
                          const float* __restrict__ Xf32,
                          const unsigned short* __restrict__ Wt,
                          const float* __restrict__ bias,
                          unsigned short* __restrict__ Y,
                          float* __restrict__ Yf,
                          int N, int K, int do_relu) {
    __shared__ unsigned short Ws[128 * 128];  // 32 KB, rows of 256 B, XOR-swizzled
    const int t = threadIdx.x;
    const int wv = t >> 6;
    const int lane = t & 63;
    const int lr = lane & 15;
    const int kb = lane >> 4;
    const int row0 = blockIdx.x * 64 + wv * 16;

    f32x4 acc[8];
#pragma unroll
    for (int i = 0; i < 8; ++i) acc[i] = (f32x4){0.f, 0.f, 0.f, 0.f};

    int arow = row0 + lr;
    if (arow >= N) arow = N - 1;
    const unsigned short* xrow = X ? X + (size_t)arow * K : nullptr;
    const float* xrowf = Xf32 ? Xf32 + (size_t)arow * K : nullptr;

    const int nch = K >> 7;
    for (int kc = 0; kc < nch; ++kc) {
        if (kc) __syncthreads();
#pragma unroll
        for (int i = 0; i < 8; ++i) {
            int li = t + i * 256;
            int r = li >> 4;
            int cb = (li & 15) << 4;
            int4 v = *(const int4*)(Wt + (size_t)r * K + (kc << 7) + (cb >> 1));
            *(int4*)((char*)Ws + r * 256 + (cb ^ ((r & 7) << 4))) = v;
        }
        short8v a[4];
        if (xrow) {
#pragma unroll
            for (int ks = 0; ks < 4; ++ks)
                a[ks] = *(const short8v*)(xrow + (kc << 7) + ks * 32 + kb * 8);
        } else {
#pragma unroll
            for (int ks = 0; ks < 4; ++ks) {
                const float* p = xrowf + (kc << 7) + ks * 32 + kb * 8;
                float4 f0 = *(const float4*)p;
                float4 f1 = *(const float4*)(p + 4);
                short8v av;
                av[0] = (short)f2bs(f0.x); av[1] = (short)f2bs(f0.y);
                av[2] = (short)f2bs(f0.z); av[3] = (short)f2bs(f0.w);
                av[4] = (short)f2bs(f1.x); av[5] = (short)f2bs(f1.y);
                av[6] = (short)f2bs(f1.z); av[7] = (short)f2bs(f1.w);
                a[ks] = av;
            }
        }
        __syncthreads();
#pragma unroll
        for (int ks = 0; ks < 4; ++ks) {
            int ofs = ks * 64 + kb * 16;
#pragma unroll
            for (int ct = 0; ct < 8; ++ct) {
                int c = ct * 16 + lr;
                short8v b = *(const short8v*)((const char*)Ws + c * 256 + (ofs ^ ((c & 7) << 4)));
                acc[ct] = __builtin_amdgcn_mfma_f32_16x16x32_bf16(a[ks], b, acc[ct], 0, 0, 0);
            }
        }
    }
#pragma unroll
    for (int ct = 0; ct < 8; ++ct) {
        int col = ct * 16 + lr;
        float bv = bias ? bias[col] : 0.f;
#pragma unroll
        for (int r = 0; r < 4; ++r) {
            int grow = row0 + kb * 4 + r;
            if (grow < N) {
                float v = acc[ct][r] + bv;
                if (do_relu) v = fmaxf(v, 0.f);
                if (Yf) Yf[(size_t)grow * H + col] = v;
                else    Y[(size_t)grow * H + col] = f2bs(v);
            }
        }
    }
}

// ---------------- CSR build phase 1: bin edges into 8 XCD buckets ----------------
// lig entry: uint64 (e<<32)|(d<<17)|s ; tgt entry: uint32 (d<<17)|s
__global__ void zero_gcur(int* __restrict__ g) {
    if (threadIdx.x < 16) g[threadIdx.x] = 0;
}

__launch_bounds__(256)
__global__ void bin_edges(const int* __restrict__ es, const int* __restrict__ ed,
                          unsigned long long* __restrict__ bkt_l, unsigned int* __restrict__ bkt_t,
                          int* __restrict__ gcur, int E) {
    __shared__ int h[16];
    __shared__ int base_s[16];
    int t = threadIdx.x;
    int lane = t & 63;
    if (t < 16) h[t] = 0;
    __syncthreads();
    int chunk = (E + gridDim.x - 1) / gridDim.x;
    int beg = blockIdx.x * chunk;
    int end = min(beg + chunk, E);
    // pass 1: wave-aggregated counting
    for (int e0 = beg; e0 < end; e0 += 256) {
        int e = e0 + t;
        int bl = -1, bt = -1;
        if (e < end) { bl = es[e] / RL; bt = ed[e] / RT; }
#pragma unroll
        for (int b = 0; b < 8; ++b) {
            unsigned long long m = __ballot(bl == b);
            if (lane == 0 && m) atomicAdd(&h[b], __popcll(m));
            m = __ballot(bt == b);
            if (lane == 0 && m) atomicAdd(&h[8 + b], __popcll(m));
        }
    }
    __syncthreads();
    if (t < 16) {
        base_s[t] = atomicAdd(&gcur[t], h[t]);
        h[t] = 0;
    }
    __syncthreads();
    // pass 2: write with wave-aggregated rank (contiguous runs -> full-line writes)
    for (int e0 = beg; e0 < end; e0 += 256) {
        int e = e0 + t;
        int s = 0, d = 0, bl = -1, bt = -1;
        if (e < end) { s = es[e]; d = ed[e]; bl = s / RL; bt = d / RT; }
        unsigned int low = ((unsigned int)d << 17) | (unsigned int)s;
#pragma unroll
        for (int b = 0; b < 8; ++b) {
            unsigned long long m = __ballot(bl == b);
            if (m) {
                int leader = __ffsll((unsigned long long)m) - 1;
                int rank = __popcll(m & ((1ULL << lane) - 1ULL));
                int wbase = 0;
                if (lane == leader) wbase = atomicAdd(&h[b], __popcll(m));
                wbase = __shfl(wbase, leader);
                if (bl == b) {
                    int i = min(base_s[b] + wbase + rank, CAP - 1);
                    bkt_l[(size_t)b * CAP + i] = ((unsigned long long)(unsigned int)e << 32) | low;
                }
            }
            m = __ballot(bt == b);
            if (m) {
                int leader = __ffsll((unsigned long long)m) - 1;
                int rank = __popcll(m & ((1ULL << lane) - 1ULL));
                int wbase = 0;
                if (lane == leader) wbase = atomicAdd(&h[8 + b], __popcll(m));
                wbase = __shfl(wbase, leader);
                if (bt == b) {
                    int i = min(base_s[8 + b] + wbase + rank, CAP - 1);
                    bkt_t[(size_t)b * CAP + i] = low;
                }
            }
        }
    }
}

// ---------------- phase 2a: per-slice LDS histogram, NO global atomics ----------------
// blocks 0..255: lig (p = bi&7, slice = bi>>3); blocks 256..511: tgt.
__launch_bounds__(256)
__global__ void count_slices(const unsigned long long* __restrict__ bkt_l,
                             const unsigned int* __restrict__ bkt_t,
                             const int* __restrict__ gcur,
                             int* __restrict__ cnts_l, int* __restrict__ cnts_t) {
    __shared__ int h[RL];  // 50 KB
    int bi = blockIdx.x;
    int t = threadIdx.x;
    if (bi < 256) {
        int p = bi & 7, slice = bi >> 3;
        for (int j = t; j < RL; j += 256) h[j] = 0;
        __syncthreads();
        int n = min(gcur[p], CAP);
        int ss = (n + NSLICE - 1) / NSLICE;
        int beg = slice * ss, end = min(beg + ss, n);
        const unsigned long long* b = bkt_l + (size_t)p * CAP;
        for (int i = beg + t; i < end; i += 256)
            atomicAdd(&h[((unsigned int)b[i] & 0x1FFFF) - p * RL], 1);
        __syncthreads();
        int* dst = cnts_l + (size_t)slice * N_LIG + p * RL;
        for (int j = t; j < RL; j += 256) dst[j] = h[j];
    } else {
        int k = bi - 256;
        int p = k & 7, slice = k >> 3;
        for (int j = t; j < RT; j += 256) h[j] = 0;
        __syncthreads();
        int n = min(gcur[8 + p], CAP);
        int ss = (n + NSLICE - 1) / NSLICE;
        int beg = slice * ss, end = min(beg + ss, n);
        const unsigned int* b = bkt_t + (size_t)p * CAP;
        for (int i = beg + t; i < end; i += 256)
            atomicAdd(&h[(int)(b[i] >> 17) - p * RT], 1);
        __syncthreads();
        int* dst = cnts_t + (size_t)slice * N_TGT + p * RT;
        for (int j = t; j < RT; j += 256) dst[j] = h[j];
    }
}

// ---------------- merged scan: node totals + in-place cross-slice exclusive prefix ----------------
__global__ void scan_block2(int* __restrict__ cnts_l, int* __restrict__ out_l,
                            int* __restrict__ bs_l, int nL, int nbL,
                            int* __restrict__ cnts_t, int* __restrict__ out_t,
                            int* __restrict__ bs_t, int nT) {
    __shared__ int ts[256];
    int* cnts; int* out; int* bsum; int n; int bi; size_t N;
    if ((int)blockIdx.x < nbL) { cnts = cnts_l; out = out_l; bsum = bs_l; n = nL; bi = blockIdx.x; N = N_LIG; }
    else { cnts = cnts_t; out = out_t; bsum = bs_t; n = nT; bi = blockIdx.x - nbL; N = N_TGT; }
    int t = threadIdx.x;
    int base = bi * 1024 + t * 4;
    int v[4] = {0, 0, 0, 0};
    for (int sl = 0; sl < NSLICE; ++sl) {
        size_t o = (size_t)sl * N + base;
#pragma unroll
        for (int i = 0; i < 4; i++) {
            if (base + i < n) {
                int c = cnts[o + i];
                cnts[o + i] = v[i];   // becomes exclusive prefix across slices
                v[i] += c;
            }
        }
    }
    int s = v[0] + v[1] + v[2] + v[3];
    ts[t] = s;
    __syncthreads();
    for (int ofs = 1; ofs < 256; ofs <<= 1) {
        int x = (t >= ofs) ? ts[t - ofs] : 0;
        __syncthreads();
        ts[t] += x;
        __syncthreads();
    }
    int run = (t == 0) ? 0 : ts[t - 1];
    if (t == 255) bsum[bi] = ts[255];
#pragma unroll
    for (int i = 0; i < 4; i++) {
        if (base + i < n) out[base + i] = run;
        run += v[i];
    }
}

__global__ void scan_top2(int* __restrict__ bs_l, int nbL, int* __restrict__ bs_t, int nbT) {
    __shared__ int ts[256];
    int* bsum = (blockIdx.x == 0) ? bs_l : bs_t;
    int nb = (blockIdx.x == 0) ? nbL : nbT;
    int t = threadIdx.x;
    ts[t] = (t < nb) ? bsum[t] : 0;
    __syncthreads();
    for (int ofs = 1; ofs < 256; ofs <<= 1) {
        int x = (t >= ofs) ? ts[t - ofs] : 0;
        __syncthreads();
        ts[t] += x;
        __syncthreads();
    }
    int excl = (t == 0) ? 0 : ts[t - 1];
    if (t < nb) bsum[t] = excl;
}

__global__ void add_off2(int* __restrict__ rp_l, const int* __restrict__ bs_l,
                         int* __restrict__ rp_t, const int* __restrict__ bs_t) {
    int i = blockIdx.x * blockDim.x + threadIdx.x;
    if (i < N_LIG) {
        rp_l[i] += bs_l[i >> 10];
        if (i == 0) rp_l[N_LIG] = NEDGE;
    } else if (i < N_LIG + N_TGT) {
        int j = i - N_LIG;
        rp_t[j] += bs_t[j >> 10];
        if (j == 0) rp_t[N_TGT] = NEDGE;
    }
}

// ---------------- phase 2b: fill CSR via LDS cursors (no global atomics) ----------------
__launch_bounds__(256)
__global__ void fill_slices(const unsigned long long* __restrict__ bkt_l,
                            const unsigned int* __restrict__ bkt_t,
                            const int* __restrict__ gcur,
                            const int* __restrict__ rowptr_l, const int* __restrict__ rowptr_t,
                            const int* __restrict__ cnts_l, const int* __restrict__ cnts_t,
                            int2* __restrict__ elist_l, int* __restrict__ nbr_t) {
    __shared__ int cur[RL];  // 50 KB
    int bi = blockIdx.x;
    int t = threadIdx.x;
    if (bi < 256) {
        int p = bi & 7, slice = bi >> 3;
        const int* rp = rowptr_l + p * RL;
        const int* pf = cnts_l + (size_t)slice * N_LIG + p * RL;
        for (int j = t; j < RL; j += 256) cur[j] = rp[j] + pf[j];
        __syncthreads();
        int n = min(gcur[p], CAP);
        int ss = (n + NSLICE - 1) / NSLICE;
        int beg = slice * ss, end = min(beg + ss, n);
        const unsigned long long* b = bkt_l + (size_t)p * CAP;
        for (int i = beg + t; i < end; i += 256) {
            unsigned long long v = b[i];
            unsigned int low = (unsigned int)v;
            int pos = atomicAdd(&cur[(low & 0x1FFFF) - p * RL], 1);
            elist_l[pos] = make_int2((low >> 17) & 0x7FFF, (int)(v >> 32));
        }
    } else {
        int k = bi - 256;
        int p = k & 7, slice = k >> 3;
        const int* rp = rowptr_t + p * RT;
        const int* pf = cnts_t + (size_t)slice * N_TGT + p * RT;
        for (int j = t; j < RT; j += 256) cur[j] = rp[j] + pf[j];
        __syncthreads();
        int n = min(gcur[8 + p], CAP);
        int ss = (n + NSLICE - 1) / NSLICE;
        int beg = slice * ss, end = min(beg + ss, n);
        const unsigned int* b = bkt_t + (size_t)p * CAP;
        for (int i = beg + t; i < end; i += 256) {
            unsigned int v = b[i];
            int pos = atomicAdd(&cur[(v >> 17) - p * RT], 1);
            nbr_t[pos] = v & 0x1FFFF;
        }
    }
}

// ---------------- gather-mean (bf16 in/out, fp32 accum): one wave per node ----------------
__launch_bounds__(256)
__global__ void gather_mean_bf16(const unsigned short* __restrict__ feat,
                                 const int* __restrict__ rowptr, const int* __restrict__ nbr,
                                 int stride, unsigned short* __restrict__ out, int N) {
    int wid = (blockIdx.x * blockDim.x + threadIdx.x) >> 6;
    if (wid >= N) return;
    int lane = threadIdx.x & 63;
    int beg = rowptr[wid], end = rowptr[wid + 1];
    const unsigned int* f = (const unsigned int*)feat;  // 2 bf16 per uint
    float ax = 0.f, ay = 0.f;
    int j = beg;
    for (; j + 8 <= end; j += 8) {
        unsigned int v[8];
#pragma unroll
        for (int q = 0; q < 8; ++q) v[q] = f[(size_t)nbr[(j + q) * stride] * 64 + lane];
#pragma unroll
        for (int q = 0; q < 8; ++q) { ax += bs2f(v[q] & 0xffff); ay += bs2f(v[q] >> 16); }
    }
    for (; j + 2 <= end; j += 2) {
        unsigned int v0 = f[(size_t)nbr[(j + 0) * stride] * 64 + lane];
        unsigned int v1 = f[(size_t)nbr[(j + 1) * stride] * 64 + lane];
        ax += bs2f(v0 & 0xffff) + bs2f(v1 & 0xffff);
        ay += bs2f(v0 >> 16) + bs2f(v1 >> 16);
    }
    for (; j < end; ++j) {
        unsigned int v = f[(size_t)nbr[j * stride] * 64 + lane];
        ax += bs2f(v & 0xffff);
        ay += bs2f(v >> 16);
    }
    float inv = 1.f / (float)max(end - beg, 1);
    unsigned int o = (unsigned int)f2bs(ax * inv) | ((unsigned int)f2bs(ay * inv) << 16);
    ((unsigned int*)out)[(size_t)wid * 64 + lane] = o;
}

// ---------------- edge MLP, ligand-major CSR order ----------------
__launch_bounds__(256)
__global__ void edge_mlp_csr(const float* __restrict__ A, const unsigned short* __restrict__ B16,
                             const int* __restrict__ rowptr, const int2* __restrict__ elist,
                             const float* __restrict__ Wp2, const float* __restrict__ bp2,
                             float* __restrict__ out, int N) {
    int w = (blockIdx.x * blockDim.x + threadIdx.x) >> 6;
    if (w >= N) return;
    int lane = threadIdx.x & 63;
    int g = lane >> 4, l16 = lane & 15;
    int beg = rowptr[w], end = rowptr[w + 1];
    if (beg == end) return;
    float4 a0 = *(const float4*)&A[(size_t)w * H + l16 * 8];
    float4 a1 = *(const float4*)&A[(size_t)w * H + l16 * 8 + 4];
    float4 w0 = *(const float4*)&Wp2[l16 * 8];
    float4 w1 = *(const float4*)&Wp2[l16 * 8 + 4];
    float bp = bp2[0];
    for (int p = beg + g; p < end; p += 4) {
        int2 de = elist[p];
        uint4 ub = *(const uint4*)&B16[(size_t)de.x * H + l16 * 8];
        float acc =
            fmaxf(a0.x + bs2f(ub.x & 0xffff), 0.f) * w0.x +
            fmaxf(a0.y + bs2f(ub.x >> 16), 0.f) * w0.y +
            fmaxf(a0.z + bs2f(ub.y & 0xffff), 0.f) * w0.z +
            fmaxf(a0.w + bs2f(ub.y >> 16), 0.f) * w0.w +
            fmaxf(a1.x + bs2f(ub.z & 0xffff), 0.f) * w1.x +
            fmaxf(a1.y + bs2f(ub.z >> 16), 0.f) * w1.y +
            fmaxf(a1.z + bs2f(ub.w & 0xffff), 0.f) * w1.z +
            fmaxf(a1.w + bs2f(ub.w >> 16), 0.f) * w1.w;
        acc += __shfl_xor(acc, 8);
        acc += __shfl_xor(acc, 4);
        acc += __shfl_xor(acc, 2);
        acc += __shfl_xor(acc, 1);
        if (l16 == 0) out[de.y] = acc + bp;
    }
}

extern "C" void kernel_launch(void* const* d_in, const int* in_sizes, int n_in,
                              void* d_out, int out_size, void* d_ws, size_t ws_size,
                              hipStream_t stream) {
    const float* x_lig = (const float*)d_in[0];
    const float* x_tgt = (const float*)d_in[1];
    const int* es = (const int*)d_in[2];
    const int* ed = (const int*)d_in[3];
    const float* W_lig = (const float*)d_in[4];
    const float* b_lig = (const float*)d_in[5];
    const float* W_tgt = (const float*)d_in[6];
    const float* b_tgt = (const float*)d_in[7];
    const float* W1f = (const float*)d_in[8];
    const float* b1f = (const float*)d_in[9];
    const float* W1r = (const float*)d_in[10];
    const float* b1r = (const float*)d_in[11];
    const float* W2f = (const float*)d_in[12];
    const float* b2f = (const float*)d_in[13];
    const float* W2r = (const float*)d_in[14];
    const float* b2r = (const float*)d_in[15];
    const float* Wp1 = (const float*)d_in[16];
    const float* bp1 = (const float*)d_in[17];
    const float* Wp2 = (const float*)d_in[18];
    const float* bp2 = (const float*)d_in[19];
    float* out = (float*)d_out;

    char* base = (char*)d_ws;
    size_t off = 0;
    auto alloc = [&](size_t bytes) { char* p = base + off; off = (off + bytes + 255) & ~(size_t)255; return p; };
    unsigned short* L0 = (unsigned short*)alloc((size_t)N_LIG * H * 2);
    unsigned short* L1 = (unsigned short*)alloc((size_t)N_LIG * H * 2);
    unsigned short* T0 = (unsigned short*)alloc((size_t)N_TGT * H * 2);
    unsigned short* T1 = (unsigned short*)alloc((size_t)N_TGT * H * 2);  // agg_t / B16
    float* Af = (float*)alloc((size_t)N_LIG * H * 4);                    // 51.2 MB
    unsigned short* Wt_tgt = (unsigned short*)alloc((size_t)128 * 1280 * 2);
    unsigned short* Wt1f = (unsigned short*)alloc(128 * 128 * 2);
    unsigned short* Wt1r = (unsigned short*)alloc(128 * 128 * 2);
    unsigned short* Wt2f = (unsigned short*)alloc(128 * 128 * 2);
    unsigned short* Wt2r = (unsigned short*)alloc(128 * 128 * 2);
    unsigned short* WtA = (unsigned short*)alloc(128 * 128 * 2);
    unsigned short* WtB = (unsigned short*)alloc(128 * 128 * 2);
    int* cnts_l = (int*)alloc((size_t)NSLICE * N_LIG * 4);   // 12.8 MB
    int* cnts_t = (int*)alloc((size_t)NSLICE * N_TGT * 4);   // 2.56 MB
    int* rowptr_l = (int*)alloc((N_LIG + 4) * 4);
    int* rowptr_t = (int*)alloc((N_TGT + 4) * 4);
    int* bsum_l = (int*)alloc(256 * 4);
    int* bsum_t = (int*)alloc(256 * 4);
    int* gcur = (int*)alloc(16 * 4);
    int2* elist_l = (int2*)alloc((size_t)NEDGE * 8);  // (d, edge_id), ligand-CSR order
    int* nbr_t = (int*)alloc((size_t)NEDGE * 4);
    unsigned long long* bkt_l = (unsigned long long*)alloc((size_t)NXCD * CAP * 8);  // 8.4 MB
    unsigned int* bkt_t = (unsigned int*)alloc((size_t)NXCD * CAP * 4);              // 4.2 MB

    const int ligBlocks = (N_LIG + 63) / 64;
    const int tgtBlocks = (N_TGT + 63) / 64;
    const int nbL = (N_LIG + 1023) / 1024;   // 98
    const int nbT = (N_TGT + 1023) / 1024;   // 20

    // 0. weight prep (transpose + bf16)
    transpose_w<<<(1280 * 128 + 255) / 256, 256, 0, stream>>>(W_tgt, Wt_tgt, 1280);
    P6 p6;
    p6.w[0] = W1f; p6.o[0] = Wt1f;
    p6.w[1] = W1r; p6.o[1] = Wt1r;
    p6.w[2] = W2f; p6.o[2] = Wt2f;
    p6.w[3] = W2r; p6.o[3] = Wt2r;
    p6.w[4] = Wp1;           p6.o[4] = WtA;
    p6.w[5] = Wp1 + 128 * H; p6.o[5] = WtB;
    transpose6<<<6 * 64, 256, 0, stream>>>(p6);

    // 1. node embeddings (x_tgt converted to bf16 in-register inside the GEMM)
    lin4_bf16<<<(N_LIG * 16 + 255) / 256, 256, 0, stream>>>(x_lig, W_lig, b_lig, L0, N_LIG);
    gemm_bf16<<<tgtBlocks, 256, 0, stream>>>(nullptr, x_tgt, Wt_tgt, b_tgt, T0, nullptr, N_TGT, 1280, 0);

    // 2. CSR build: bin -> count_slices -> scan (merged prefix) -> fill_slices
    zero_gcur<<<1, 64, 0, stream>>>(gcur);
    bin_edges<<<512, 256, 0, stream>>>(es, ed, bkt_l, bkt_t, gcur, NEDGE);
    count_slices<<<512, 256, 0, stream>>>(bkt_l, bkt_t, gcur, cnts_l, cnts_t);
    scan_block2<<<nbL + nbT, 256, 0, stream>>>(cnts_l, rowptr_l, bsum_l, N_LIG, nbL,
                                               cnts_t, rowptr_t, bsum_t, N_TGT);
    scan_top2<<<2, 256, 0, stream>>>(bsum_l, nbL, bsum_t, nbT);
    add_off2<<<(N_LIG + N_TGT + 255) / 256, 256, 0, stream>>>(rowptr_l, bsum_l, rowptr_t, bsum_t);
    fill_slices<<<512, 256, 0, stream>>>(bkt_l, bkt_t, gcur, rowptr_l, rowptr_t,
                                         cnts_l, cnts_t, elist_l, nbr_t);

    // 3. two conv layers (gather-mean + MFMA GEMM)
    const unsigned short* Wtf[2] = {Wt1f, Wt2f};
    const float* bfp[2] = {b1f, b2f};
    const unsigned short* Wtr[2] = {Wt1r, Wt2r};
    const float* brp[2] = {b1r, b2r};
    for (int layer = 0; layer < 2; ++layer) {
        gather_mean_bf16<<<(N_TGT * 64 + 255) / 256, 256, 0, stream>>>(L0, rowptr_t, nbr_t, 1, T1, N_TGT);
        gather_mean_bf16<<<(N_LIG * 64 + 255) / 256, 256, 0, stream>>>(T0, rowptr_l, (const int*)elist_l, 2, L1, N_LIG);
        gemm_bf16<<<tgtBlocks, 256, 0, stream>>>(T1, nullptr, Wtf[layer], bfp[layer], T0, nullptr, N_TGT, 128, 1);
        gemm_bf16<<<ligBlocks, 256, 0, stream>>>(L1, nullptr, Wtr[layer], brp[layer], L0, nullptr, N_LIG, 128, 1);
    }

    // 4. edge-MLP factorization: A (fp32) = h_lig @ Wp1_top; B (bf16) = h_tgt @ Wp1_bot + bp1
    gemm_bf16<<<ligBlocks, 256, 0, stream>>>(L0, nullptr, WtA, nullptr, nullptr, Af, N_LIG, 128, 0);
    gemm_bf16<<<tgtBlocks, 256, 0, stream>>>(T0, nullptr, WtB, bp1, T1, nullptr, N_TGT, 128, 0);

    // 5. per-edge, ligand-major: pred = relu(A[s]+B[d]) . Wp2 + bp2
    edge_mlp_csr<<<(N_LIG * 64 + 255) / 256, 256, 0, stream>>>(
        Af, T1, rowptr_l, elist_l, Wp2, bp2, out, N_LIG);
}

// Round 9
// 459.709 us; speedup vs baseline: 16.4429x; 1.0763x over previous
//
#include <hip/hip_runtime.h>
#include <hip/hip_bf16.h>

#define N_LIG 100000
#define N_TGT 20000
#define NEDGE 1000000
#define H 128
#define NXCD 8
#define RL 12500   // ligand ids per partition (8*12500 = 100000)
#define RT 2500    // target ids per partition (8*2500 = 20000)
#define CAP 131072 // per-bucket capacity (mean 125000, sigma ~331)
#define NSLICE 32  // sub-slices per bucket for count/fill

typedef __attribute__((ext_vector_type(8))) short short8v;
typedef __attribute__((ext_vector_type(4))) float f32x4;

// ---- bf16 helpers (manual RTN-even, bit ops only) ----
__device__ __forceinline__ unsigned short f2bs(float f) {
    unsigned int u = __float_as_uint(f);
    u += 0x7fff + ((u >> 16) & 1);
    return (unsigned short)(u >> 16);
}
__device__ __forceinline__ float bs2f(unsigned int s) {
    return __uint_as_float(s << 16);
}

// ---------------- weight transpose+convert: W[K][128] f32 -> Wt[128][K] bf16 ----------------
__global__ void transpose_w(const float* __restrict__ W, unsigned short* __restrict__ Wt, int K) {
    int idx = blockIdx.x * blockDim.x + threadIdx.x;
    if (idx >= K * 128) return;
    int k = idx >> 7, c = idx & 127;
    Wt[(size_t)c * K + k] = f2bs(W[idx]);
}

// six 128x128 transposes in one launch
struct P6 { const float* w[6]; unsigned short* o[6]; };
__global__ void transpose6(P6 p) {
    int idx = blockIdx.x * blockDim.x + threadIdx.x;  // 6*16384
    int which = idx >> 14;
    int rem = idx & 16383;
    int k = rem >> 7, c = rem & 127;
    p.o[which][(size_t)c * 128 + k] = f2bs(p.w[which][rem]);
}

// ---------------- ligand embed: K=4, bf16 out ----------------
__global__ void lin4_bf16(const float* __restrict__ X, const float* __restrict__ W,
                          const float* __restrict__ b, unsigned short* __restrict__ Y, int N) {
    int idx = blockIdx.x * blockDim.x + threadIdx.x;  // N*16, 8 cols each
    if (idx >= N * 16) return;
    int r = idx >> 4;
    int c = (idx & 15) * 8;
    float x0 = X[r * 4 + 0], x1 = X[r * 4 + 1], x2 = X[r * 4 + 2], x3 = X[r * 4 + 3];
    unsigned int o[4];
#pragma unroll
    for (int p = 0; p < 4; ++p) {
        float v0 = b[c + 2 * p] + x0 * W[c + 2 * p] + x1 * W[H + c + 2 * p] +
                   x2 * W[2 * H + c + 2 * p] + x3 * W[3 * H + c + 2 * p];
        float v1 = b[c + 2 * p + 1] + x0 * W[c + 2 * p + 1] + x1 * W[H + c + 2 * p + 1] +
                   x2 * W[2 * H + c + 2 * p + 1] + x3 * W[3 * H + c + 2 * p + 1];
        o[p] = (unsigned int)f2bs(v0) | ((unsigned int)f2bs(v1) << 16);
    }
    uint4 u = make_uint4(o[0], o[1], o[2], o[3]);
    *(uint4*)&Y[(size_t)r * H + c] = u;
}

// ---------------- MFMA GEMM: act(X[N][K] @ W + bias) -> Y (bf16) or Yf (fp32) ----------------
__launch_bounds__(256)
__global__ void gemm_bf16(const unsigned short* __restrict__ X,
                          const float* __restrict__ Xf32,
                          const unsigned short* __restrict__ Wt,
                          const float* __restrict__ bias,
                          unsigned short* __restrict__ Y,
                          float* __restrict__ Yf,
                          int N, int K, int do_relu) {
    __shared__ unsigned short Ws[128 * 128];  // 32 KB, rows of 256 B, XOR-swizzled
    const int t = threadIdx.x;
    const int wv = t >> 6;
    const int lane = t & 63;
    const int lr = lane & 15;
    const int kb = lane >> 4;
    const int row0 = blockIdx.x * 64 + wv * 16;

    f32x4 acc[8];
#pragma unroll
    for (int i = 0; i < 8; ++i) acc[i] = (f32x4){0.f, 0.f, 0.f, 0.f};

    int arow = row0 + lr;
    if (arow >= N) arow = N - 1;
    const unsigned short* xrow = X ? X + (size_t)arow * K : nullptr;
    const float* xrowf = Xf32 ? Xf32 + (size_t)arow * K : nullptr;

    const int nch = K >> 7;
    for (int kc = 0; kc < nch; ++kc) {
        if (kc) __syncthreads();
#pragma unroll
        for (int i = 0; i < 8; ++i) {
            int li = t + i * 256;
            int r = li >> 4;
            int cb = (li & 15) << 4;
            int4 v = *(const int4*)(Wt + (size_t)r * K + (kc << 7) + (cb >> 1));
            *(int4*)((char*)Ws + r * 256 + (cb ^ ((r & 7) << 4))) = v;
        }
        short8v a[4];
        if (xrow) {
#pragma unroll
            for (int ks = 0; ks < 4; ++ks)
                a[ks] = *(const short8v*)(xrow + (kc << 7) + ks * 32 + kb * 8);
        } else {
#pragma unroll
            for (int ks = 0; ks < 4; ++ks) {
                const float* p = xrowf + (kc << 7) + ks * 32 + kb * 8;
                float4 f0 = *(const float4*)p;
                float4 f1 = *(const float4*)(p + 4);
                short8v av;
                av[0] = (short)f2bs(f0.x); av[1] = (short)f2bs(f0.y);
                av[2] = (short)f2bs(f0.z); av[3] = (short)f2bs(f0.w);
                av[4] = (short)f2bs(f1.x); av[5] = (short)f2bs(f1.y);
                av[6] = (short)f2bs(f1.z); av[7] = (short)f2bs(f1.w);
                a[ks] = av;
            }
        }
        __syncthreads();
#pragma unroll
        for (int ks = 0; ks < 4; ++ks) {
            int ofs = ks * 64 + kb * 16;
#pragma unroll
            for (int ct = 0; ct < 8; ++ct) {
                int c = ct * 16 + lr;
                short8v b = *(const short8v*)((const char*)Ws + c * 256 + (ofs ^ ((c & 7) << 4)));
                acc[ct] = __builtin_amdgcn_mfma_f32_16x16x32_bf16(a[ks], b, acc[ct], 0, 0, 0);
            }
        }
    }
#pragma unroll
    for (int ct = 0; ct < 8; ++ct) {
        int col = ct * 16 + lr;
        float bv = bias ? bias[col] : 0.f;
#pragma unroll
        for (int r = 0; r < 4; ++r) {
            int grow = row0 + kb * 4 + r;
            if (grow < N) {
                float v = acc[ct][r] + bv;
                if (do_relu) v = fmaxf(v, 0.f);
                if (Yf) Yf[(size_t)grow * H + col] = v;
                else    Y[(size_t)grow * H + col] = f2bs(v);
            }
        }
    }
}

// ---------------- CSR build phase 1: bin edges into 8 XCD buckets ----------------
// lig entry: uint64 (e<<32)|(d<<17)|s ; tgt entry: uint32 (d<<17)|s
__global__ void zero_gcur(int* __restrict__ g) {
    if (threadIdx.x < 16) g[threadIdx.x] = 0;
}

__launch_bounds__(256)
__global__ void bin_edges(const int* __restrict__ es, const int* __restrict__ ed,
                          unsigned long long* __restrict__ bkt_l, unsigned int* __restrict__ bkt_t,
                          int* __restrict__ gcur, int E) {
    __shared__ int h[16];
    __shared__ int base_s[16];
    int t = threadIdx.x;
    int lane = t & 63;
    if (t < 16) h[t] = 0;
    __syncthreads();
    int chunk = (E + gridDim.x - 1) / gridDim.x;
    int beg = blockIdx.x * chunk;
    int end = min(beg + chunk, E);
    // pass 1: wave-aggregated counting
    for (int e0 = beg; e0 < end; e0 += 256) {
        int e = e0 + t;
        int bl = -1, bt = -1;
        if (e < end) { bl = es[e] / RL; bt = ed[e] / RT; }
#pragma unroll
        for (int b = 0; b < 8; ++b) {
            unsigned long long m = __ballot(bl == b);
            if (lane == 0 && m) atomicAdd(&h[b], __popcll(m));
            m = __ballot(bt == b);
            if (lane == 0 && m) atomicAdd(&h[8 + b], __popcll(m));
        }
    }
    __syncthreads();
    if (t < 16) {
        base_s[t] = atomicAdd(&gcur[t], h[t]);
        h[t] = 0;
    }
    __syncthreads();
    // pass 2: write with wave-aggregated rank (contiguous runs -> full-line writes)
    for (int e0 = beg; e0 < end; e0 += 256) {
        int e = e0 + t;
        int s = 0, d = 0, bl = -1, bt = -1;
        if (e < end) { s = es[e]; d = ed[e]; bl = s / RL; bt = d / RT; }
        unsigned int low = ((unsigned int)d << 17) | (unsigned int)s;
#pragma unroll
        for (int b = 0; b < 8; ++b) {
            unsigned long long m = __ballot(bl == b);
            if (m) {
                int leader = __ffsll((unsigned long long)m) - 1;
                int rank = __popcll(m & ((1ULL << lane) - 1ULL));
                int wbase = 0;
                if (lane == leader) wbase = atomicAdd(&h[b], __popcll(m));
                wbase = __shfl(wbase, leader);
                if (bl == b) {
                    int i = min(base_s[b] + wbase + rank, CAP - 1);
                    bkt_l[(size_t)b * CAP + i] = ((unsigned long long)(unsigned int)e << 32) | low;
                }
            }
            m = __ballot(bt == b);
            if (m) {
                int leader = __ffsll((unsigned long long)m) - 1;
                int rank = __popcll(m & ((1ULL << lane) - 1ULL));
                int wbase = 0;
                if (lane == leader) wbase = atomicAdd(&h[8 + b], __popcll(m));
                wbase = __shfl(wbase, leader);
                if (bt == b) {
                    int i = min(base_s[8 + b] + wbase + rank, CAP - 1);
                    bkt_t[(size_t)b * CAP + i] = low;
                }
            }
        }
    }
}

// ---------------- phase 2a: per-slice LDS histogram, NO global atomics ----------------
__launch_bounds__(256)
__global__ void count_slices(const unsigned long long* __restrict__ bkt_l,
                             const unsigned int* __restrict__ bkt_t,
                             const int* __restrict__ gcur,
                             int* __restrict__ cnts_l, int* __restrict__ cnts_t) {
    __shared__ int h[RL];  // 50 KB
    int bi = blockIdx.x;
    int t = threadIdx.x;
    if (bi < 256) {
        int p = bi & 7, slice = bi >> 3;
        for (int j = t; j < RL; j += 256) h[j] = 0;
        __syncthreads();
        int n = min(gcur[p], CAP);
        int ss = (n + NSLICE - 1) / NSLICE;
        int beg = slice * ss, end = min(beg + ss, n);
        const unsigned long long* b = bkt_l + (size_t)p * CAP;
        for (int i = beg + t; i < end; i += 256)
            atomicAdd(&h[((unsigned int)b[i] & 0x1FFFF) - p * RL], 1);
        __syncthreads();
        int* dst = cnts_l + (size_t)slice * N_LIG + p * RL;
        for (int j = t; j < RL; j += 256) dst[j] = h[j];
    } else {
        int k = bi - 256;
        int p = k & 7, slice = k >> 3;
        for (int j = t; j < RT; j += 256) h[j] = 0;
        __syncthreads();
        int n = min(gcur[8 + p], CAP);
        int ss = (n + NSLICE - 1) / NSLICE;
        int beg = slice * ss, end = min(beg + ss, n);
        const unsigned int* b = bkt_t + (size_t)p * CAP;
        for (int i = beg + t; i < end; i += 256)
            atomicAdd(&h[(int)(b[i] >> 17) - p * RT], 1);
        __syncthreads();
        int* dst = cnts_t + (size_t)slice * N_TGT + p * RT;
        for (int j = t; j < RT; j += 256) dst[j] = h[j];
    }
}

// ---------------- merged scan: node totals + in-place cross-slice exclusive prefix ----------------
__global__ void scan_block2(int* __restrict__ cnts_l, int* __restrict__ out_l,
                            int* __restrict__ bs_l, int nL, int nbL,
                            int* __restrict__ cnts_t, int* __restrict__ out_t,
                            int* __restrict__ bs_t, int nT) {
    __shared__ int ts[256];
    int* cnts; int* out; int* bsum; int n; int bi; size_t N;
    if ((int)blockIdx.x < nbL) { cnts = cnts_l; out = out_l; bsum = bs_l; n = nL; bi = blockIdx.x; N = N_LIG; }
    else { cnts = cnts_t; out = out_t; bsum = bs_t; n = nT; bi = blockIdx.x - nbL; N = N_TGT; }
    int t = threadIdx.x;
    int base = bi * 1024 + t * 4;
    int v[4] = {0, 0, 0, 0};
    for (int sl = 0; sl < NSLICE; ++sl) {
        size_t o = (size_t)sl * N + base;
#pragma unroll
        for (int i = 0; i < 4; i++) {
            if (base + i < n) {
                int c = cnts[o + i];
                cnts[o + i] = v[i];   // becomes exclusive prefix across slices
                v[i] += c;
            }
        }
    }
    int s = v[0] + v[1] + v[2] + v[3];
    ts[t] = s;
    __syncthreads();
    for (int ofs = 1; ofs < 256; ofs <<= 1) {
        int x = (t >= ofs) ? ts[t - ofs] : 0;
        __syncthreads();
        ts[t] += x;
        __syncthreads();
    }
    int run = (t == 0) ? 0 : ts[t - 1];
    if (t == 255) bsum[bi] = ts[255];
#pragma unroll
    for (int i = 0; i < 4; i++) {
        if (base + i < n) out[base + i] = run;
        run += v[i];
    }
}

__global__ void scan_top2(int* __restrict__ bs_l, int nbL, int* __restrict__ bs_t, int nbT) {
    __shared__ int ts[256];
    int* bsum = (blockIdx.x == 0) ? bs_l : bs_t;
    int nb = (blockIdx.x == 0) ? nbL : nbT;
    int t = threadIdx.x;
    ts[t] = (t < nb) ? bsum[t] : 0;
    __syncthreads();
    for (int ofs = 1; ofs < 256; ofs <<= 1) {
        int x = (t >= ofs) ? ts[t - ofs] : 0;
        __syncthreads();
        ts[t] += x;
        __syncthreads();
    }
    int excl = (t == 0) ? 0 : ts[t - 1];
    if (t < nb) bsum[t] = excl;
}

__global__ void add_off2(int* __restrict__ rp_l, const int* __restrict__ bs_l,
                         int* __restrict__ rp_t, const int* __restrict__ bs_t) {
    int i = blockIdx.x * blockDim.x + threadIdx.x;
    if (i < N_LIG) {
        rp_l[i] += bs_l[i >> 10];
        if (i == 0) rp_l[N_LIG] = NEDGE;
    } else if (i < N_LIG + N_TGT) {
        int j = i - N_LIG;
        rp_t[j] += bs_t[j >> 10];
        if (j == 0) rp_t[N_TGT] = NEDGE;
    }
}

// ---------------- phase 2b: fill CSR via LDS cursors (no global atomics) ----------------
__launch_bounds__(256)
__global__ void fill_slices(const unsigned long long* __restrict__ bkt_l,
                            const unsigned int* __restrict__ bkt_t,
                            const int* __restrict__ gcur,
                            const int* __restrict__ rowptr_l, const int* __restrict__ rowptr_t,
                            const int* __restrict__ cnts_l, const int* __restrict__ cnts_t,
                            int2* __restrict__ elist_l, int* __restrict__ nbr_t) {
    __shared__ int cur[RL];  // 50 KB
    int bi = blockIdx.x;
    int t = threadIdx.x;
    if (bi < 256) {
        int p = bi & 7, slice = bi >> 3;
        const int* rp = rowptr_l + p * RL;
        const int* pf = cnts_l + (size_t)slice * N_LIG + p * RL;
        for (int j = t; j < RL; j += 256) cur[j] = rp[j] + pf[j];
        __syncthreads();
        int n = min(gcur[p], CAP);
        int ss = (n + NSLICE - 1) / NSLICE;
        int beg = slice * ss, end = min(beg + ss, n);
        const unsigned long long* b = bkt_l + (size_t)p * CAP;
        for (int i = beg + t; i < end; i += 256) {
            unsigned long long v = b[i];
            unsigned int low = (unsigned int)v;
            int pos = atomicAdd(&cur[(low & 0x1FFFF) - p * RL], 1);
            elist_l[pos] = make_int2((low >> 17) & 0x7FFF, (int)(v >> 32));
        }
    } else {
        int k = bi - 256;
        int p = k & 7, slice = k >> 3;
        const int* rp = rowptr_t + p * RT;
        const int* pf = cnts_t + (size_t)slice * N_TGT + p * RT;
        for (int j = t; j < RT; j += 256) cur[j] = rp[j] + pf[j];
        __syncthreads();
        int n = min(gcur[8 + p], CAP);
        int ss = (n + NSLICE - 1) / NSLICE;
        int beg = slice * ss, end = min(beg + ss, n);
        const unsigned int* b = bkt_t + (size_t)p * CAP;
        for (int i = beg + t; i < end; i += 256) {
            unsigned int v = b[i];
            int pos = atomicAdd(&cur[(v >> 17) - p * RT], 1);
            nbr_t[pos] = v & 0x1FFFF;
        }
    }
}

// ---------------- gather-mean (bf16 in/out, fp32 accum): one wave per node ----------------
// optional epilogue: out = relu(mean + bias) when bias != nullptr
__launch_bounds__(256)
__global__ void gather_mean_bf16(const unsigned short* __restrict__ feat,
                                 const int* __restrict__ rowptr, const int* __restrict__ nbr,
                                 int stride, const float* __restrict__ bias,
                                 unsigned short* __restrict__ out, int N) {
    int wid = (blockIdx.x * blockDim.x + threadIdx.x) >> 6;
    if (wid >= N) return;
    int lane = threadIdx.x & 63;
    int beg = rowptr[wid], end = rowptr[wid + 1];
    const unsigned int* f = (const unsigned int*)feat;  // 2 bf16 per uint
    float ax = 0.f, ay = 0.f;
    int j = beg;
    for (; j + 8 <= end; j += 8) {
        unsigned int v[8];
#pragma unroll
        for (int q = 0; q < 8; ++q) v[q] = f[(size_t)nbr[(j + q) * stride] * 64 + lane];
#pragma unroll
        for (int q = 0; q < 8; ++q) { ax += bs2f(v[q] & 0xffff); ay += bs2f(v[q] >> 16); }
    }
    for (; j + 2 <= end; j += 2) {
        unsigned int v0 = f[(size_t)nbr[(j + 0) * stride] * 64 + lane];
        unsigned int v1 = f[(size_t)nbr[(j + 1) * stride] * 64 + lane];
        ax += bs2f(v0 & 0xffff) + bs2f(v1 & 0xffff);
        ay += bs2f(v0 >> 16) + bs2f(v1 >> 16);
    }
    for (; j < end; ++j) {
        unsigned int v = f[(size_t)nbr[j * stride] * 64 + lane];
        ax += bs2f(v & 0xffff);
        ay += bs2f(v >> 16);
    }
    float inv = 1.f / (float)max(end - beg, 1);
    float mx = ax * inv, my = ay * inv;
    if (bias) {
        mx = fmaxf(mx + bias[2 * lane], 0.f);
        my = fmaxf(my + bias[2 * lane + 1], 0.f);
    }
    unsigned int o = (unsigned int)f2bs(mx) | ((unsigned int)f2bs(my) << 16);
    ((unsigned int*)out)[(size_t)wid * 64 + lane] = o;
}

// ---------------- edge MLP, ligand-major CSR order (A and B bf16) ----------------
__launch_bounds__(256)
__global__ void edge_mlp_csr(const unsigned short* __restrict__ A16, const unsigned short* __restrict__ B16,
                             const int* __restrict__ rowptr, const int2* __restrict__ elist,
                             const float* __restrict__ Wp2, const float* __restrict__ bp2,
                             float* __restrict__ out, int N) {
    int w = (blockIdx.x * blockDim.x + threadIdx.x) >> 6;
    if (w >= N) return;
    int lane = threadIdx.x & 63;
    int g = lane >> 4, l16 = lane & 15;
    int beg = rowptr[w], end = rowptr[w + 1];
    if (beg == end) return;
    uint4 ua = *(const uint4*)&A16[(size_t)w * H + l16 * 8];
    float a[8] = {bs2f(ua.x & 0xffff), bs2f(ua.x >> 16), bs2f(ua.y & 0xffff), bs2f(ua.y >> 16),
                  bs2f(ua.z & 0xffff), bs2f(ua.z >> 16), bs2f(ua.w & 0xffff), bs2f(ua.w >> 16)};
    float4 w0 = *(const float4*)&Wp2[l16 * 8];
    float4 w1 = *(const float4*)&Wp2[l16 * 8 + 4];
    float wv[8] = {w0.x, w0.y, w0.z, w0.w, w1.x, w1.y, w1.z, w1.w};
    float bp = bp2[0];
    for (int p = beg + g; p < end; p += 4) {
        int2 de = elist[p];
        uint4 ub = *(const uint4*)&B16[(size_t)de.x * H + l16 * 8];
        float bb[8] = {bs2f(ub.x & 0xffff), bs2f(ub.x >> 16), bs2f(ub.y & 0xffff), bs2f(ub.y >> 16),
                       bs2f(ub.z & 0xffff), bs2f(ub.z >> 16), bs2f(ub.w & 0xffff), bs2f(ub.w >> 16)};
        float acc = 0.f;
#pragma unroll
        for (int q = 0; q < 8; ++q) acc += fmaxf(a[q] + bb[q], 0.f) * wv[q];
        acc += __shfl_xor(acc, 8);
        acc += __shfl_xor(acc, 4);
        acc += __shfl_xor(acc, 2);
        acc += __shfl_xor(acc, 1);
        if (l16 == 0) out[de.y] = acc + bp;
    }
}

extern "C" void kernel_launch(void* const* d_in, const int* in_sizes, int n_in,
                              void* d_out, int out_size, void* d_ws, size_t ws_size,
                              hipStream_t stream) {
    const float* x_lig = (const float*)d_in[0];
    const float* x_tgt = (const float*)d_in[1];
    const int* es = (const int*)d_in[2];
    const int* ed = (const int*)d_in[3];
    const float* W_lig = (const float*)d_in[4];
    const float* b_lig = (const float*)d_in[5];
    const float* W_tgt = (const float*)d_in[6];
    const float* b_tgt = (const float*)d_in[7];
    const float* W1f = (const float*)d_in[8];
    const float* b1f = (const float*)d_in[9];
    const float* W1r = (const float*)d_in[10];
    const float* b1r = (const float*)d_in[11];
    const float* W2f = (const float*)d_in[12];
    const float* b2f = (const float*)d_in[13];
    const float* W2r = (const float*)d_in[14];
    const float* b2r = (const float*)d_in[15];
    const float* Wp1 = (const float*)d_in[16];
    const float* bp1 = (const float*)d_in[17];
    const float* Wp2 = (const float*)d_in[18];
    const float* bp2 = (const float*)d_in[19];
    float* out = (float*)d_out;

    char* base = (char*)d_ws;
    size_t off = 0;
    auto alloc = [&](size_t bytes) { char* p = base + off; off = (off + bytes + 255) & ~(size_t)255; return p; };
    unsigned short* L0 = (unsigned short*)alloc((size_t)N_LIG * H * 2);
    unsigned short* L1 = (unsigned short*)alloc((size_t)N_LIG * H * 2);   // A16 (edge stage)
    unsigned short* T0 = (unsigned short*)alloc((size_t)N_TGT * H * 2);
    unsigned short* T1 = (unsigned short*)alloc((size_t)N_TGT * H * 2);   // agg_t / B16
    unsigned short* G  = (unsigned short*)alloc((size_t)N_TGT * H * 2);   // T0 @ Wr pre-transform
    unsigned short* Wt_tgt = (unsigned short*)alloc((size_t)128 * 1280 * 2);
    unsigned short* Wt1f = (unsigned short*)alloc(128 * 128 * 2);
    unsigned short* Wt1r = (unsigned short*)alloc(128 * 128 * 2);
    unsigned short* Wt2f = (unsigned short*)alloc(128 * 128 * 2);
    unsigned short* Wt2r = (unsigned short*)alloc(128 * 128 * 2);
    unsigned short* WtA = (unsigned short*)alloc(128 * 128 * 2);
    unsigned short* WtB = (unsigned short*)alloc(128 * 128 * 2);
    int* cnts_l = (int*)alloc((size_t)NSLICE * N_LIG * 4);   // 12.8 MB
    int* cnts_t = (int*)alloc((size_t)NSLICE * N_TGT * 4);   // 2.56 MB
    int* rowptr_l = (int*)alloc((N_LIG + 4) * 4);
    int* rowptr_t = (int*)alloc((N_TGT + 4) * 4);
    int* bsum_l = (int*)alloc(256 * 4);
    int* bsum_t = (int*)alloc(256 * 4);
    int* gcur = (int*)alloc(16 * 4);
    int2* elist_l = (int2*)alloc((size_t)NEDGE * 8);  // (d, edge_id), ligand-CSR order
    int* nbr_t = (int*)alloc((size_t)NEDGE * 4);
    unsigned long long* bkt_l = (unsigned long long*)alloc((size_t)NXCD * CAP * 8);  // 8.4 MB
    unsigned int* bkt_t = (unsigned int*)alloc((size_t)NXCD * CAP * 4);              // 4.2 MB

    const int ligBlocks = (N_LIG + 63) / 64;
    const int tgtBlocks = (N_TGT + 63) / 64;
    const int nbL = (N_LIG + 1023) / 1024;   // 98
    const int nbT = (N_TGT + 1023) / 1024;   // 20

    // 0. weight prep (transpose + bf16)
    transpose_w<<<(1280 * 128 + 255) / 256, 256, 0, stream>>>(W_tgt, Wt_tgt, 1280);
    P6 p6;
    p6.w[0] = W1f; p6.o[0] = Wt1f;
    p6.w[1] = W1r; p6.o[1] = Wt1r;
    p6.w[2] = W2f; p6.o[2] = Wt2f;
    p6.w[3] = W2r; p6.o[3] = Wt2r;
    p6.w[4] = Wp1;           p6.o[4] = WtA;
    p6.w[5] = Wp1 + 128 * H; p6.o[5] = WtB;
    transpose6<<<6 * 64, 256, 0, stream>>>(p6);

    // 1. node embeddings (x_tgt converted to bf16 in-register inside the GEMM)
    lin4_bf16<<<(N_LIG * 16 + 255) / 256, 256, 0, stream>>>(x_lig, W_lig, b_lig, L0, N_LIG);
    gemm_bf16<<<tgtBlocks, 256, 0, stream>>>(nullptr, x_tgt, Wt_tgt, b_tgt, T0, nullptr, N_TGT, 1280, 0);

    // 2. CSR build: bin -> count_slices -> scan (merged prefix) -> fill_slices
    zero_gcur<<<1, 64, 0, stream>>>(gcur);
    bin_edges<<<512, 256, 0, stream>>>(es, ed, bkt_l, bkt_t, gcur, NEDGE);
    count_slices<<<512, 256, 0, stream>>>(bkt_l, bkt_t, gcur, cnts_l, cnts_t);
    scan_block2<<<nbL + nbT, 256, 0, stream>>>(cnts_l, rowptr_l, bsum_l, N_LIG, nbL,
                                               cnts_t, rowptr_t, bsum_t, N_TGT);
    scan_top2<<<2, 256, 0, stream>>>(bsum_l, nbL, bsum_t, nbT);
    add_off2<<<(N_LIG + N_TGT + 255) / 256, 256, 0, stream>>>(rowptr_l, bsum_l, rowptr_t, bsum_t);
    fill_slices<<<512, 256, 0, stream>>>(bkt_l, bkt_t, gcur, rowptr_l, rowptr_t,
                                         cnts_l, cnts_t, elist_l, nbr_t);

    // 3. two conv layers. L-side via linearity: G = T0 @ Wr (20k rows), then
    //    L0 = relu(mean(G[d]) + br) fused in the gather epilogue (no 100k GEMM).
    const unsigned short* Wtf[2] = {Wt1f, Wt2f};
    const float* bfp[2] = {b1f, b2f};
    const unsigned short* Wtr[2] = {Wt1r, Wt2r};
    const float* brp[2] = {b1r, b2r};
    for (int layer = 0; layer < 2; ++layer) {
        gemm_bf16<<<tgtBlocks, 256, 0, stream>>>(T0, nullptr, Wtr[layer], nullptr, G, nullptr, N_TGT, 128, 0);
        gather_mean_bf16<<<(N_TGT * 64 + 255) / 256, 256, 0, stream>>>(L0, rowptr_t, nbr_t, 1, nullptr, T1, N_TGT);
        gather_mean_bf16<<<(N_LIG * 64 + 255) / 256, 256, 0, stream>>>(G, rowptr_l, (const int*)elist_l, 2, brp[layer], L0, N_LIG);
        gemm_bf16<<<tgtBlocks, 256, 0, stream>>>(T1, nullptr, Wtf[layer], bfp[layer], T0, nullptr, N_TGT, 128, 1);
    }

    // 4. edge-MLP factorization (both bf16): A = h_lig @ Wp1_top; B = h_tgt @ Wp1_bot + bp1
    gemm_bf16<<<ligBlocks, 256, 0, stream>>>(L0, nullptr, WtA, nullptr, L1, nullptr, N_LIG, 128, 0);
    gemm_bf16<<<tgtBlocks, 256, 0, stream>>>(T0, nullptr, WtB, bp1, T1, nullptr, N_TGT, 128, 0);

    // 5. per-edge, ligand-major: pred = relu(A[s]+B[d]) . Wp2 + bp2
    edge_mlp_csr<<<(N_LIG * 64 + 255) / 256, 256, 0, stream>>>(
        L1, T1, rowptr_l, elist_l, Wp2, bp2, out, N_LIG);
}